// Round 5
// baseline (2588.421 us; speedup 1.0000x reference)
//
#include <hip/hip_runtime.h>
#include <hip/hip_bf16.h>
#include <math.h>

// Problem constants
constexpr int B_ = 2;
constexpr int C_ = 64;
constexpr int H_ = 160;
constexpr int W_ = 320;
constexpr int G_ = 8;       // correlation groups
constexpr int CG_ = 8;      // channels per group
constexpr int D_ = 24;      // max disparity
constexpr int HW_ = H_ * W_;        // 51200
constexpr int DHW_ = D_ * HW_;      // 1228800
constexpr float EPS_ = 1e-5f;

// typed load/store helpers (fp32 or bf16 storage)
__device__ inline float ldf(const float* p) { return *p; }
__device__ inline float ldf(const __hip_bfloat16* p) { return __bfloat162float(*p); }
__device__ inline void stf(float* p, float v) { *p = v; }
__device__ inline void stf(__hip_bfloat16* p, float v) { *p = __float2bfloat16(v); }

// ---------------------------------------------------------------------------
// Cost volume: cv[b,g,d,h,w] = mean_c fL[b,g*8+c,h,w] * fR[b,g*8+c,h,w-d]
// ---------------------------------------------------------------------------
__global__ __launch_bounds__(320)
void cv_kernel(const float* __restrict__ fL, const float* __restrict__ fR,
               float* __restrict__ cv) {
  int w = threadIdx.x;
  int h = blockIdx.x % H_;
  int b = blockIdx.x / H_;
  int g = blockIdx.y;
  const float* pL = fL + (((size_t)b * C_ + g * CG_) * H_ + h) * W_ + w;
  const float* pR = fR + (((size_t)b * C_ + g * CG_) * H_ + h) * W_;
  float l[CG_];
#pragma unroll
  for (int c = 0; c < CG_; c++) l[c] = pL[(size_t)c * HW_];
  for (int d = 0; d < D_; d++) {
    float s = 0.f;
    if (w >= d) {
#pragma unroll
      for (int c = 0; c < CG_; c++) s += l[c] * pR[(size_t)c * HW_ + (w - d)];
    }
    cv[((((size_t)b * G_ + g) * D_ + d) * H_ + h) * W_ + w] = s * (1.f / CG_);
  }
}

// ---------------------------------------------------------------------------
// 3x3x3 conv3d, pad 1, weights OIDHW in LDS, thread = (b,d,h,w)
// ---------------------------------------------------------------------------
template <int CIN, int COUT, bool HASBIAS, typename Tin, typename Tout>
__global__ __launch_bounds__(320)
void conv3d_kernel(const Tin* __restrict__ in, const float* __restrict__ wt,
                   const float* __restrict__ bias, Tout* __restrict__ out) {
  __shared__ float lw[COUT * CIN * 27];
  for (int i = threadIdx.x; i < COUT * CIN * 27; i += 320) lw[i] = wt[i];
  __syncthreads();
  int w = threadIdx.x;
  int h = blockIdx.x % H_;
  int d = (blockIdx.x / H_) % D_;
  int b = blockIdx.x / (H_ * D_);
  float acc[COUT];
#pragma unroll
  for (int co = 0; co < COUT; co++) acc[co] = 0.f;
  for (int kd = 0; kd < 3; kd++) {
    int dd = d + kd - 1;
    if (dd < 0 || dd >= D_) continue;
    for (int kh = 0; kh < 3; kh++) {
      int hh = h + kh - 1;
      if (hh < 0 || hh >= H_) continue;
      const Tin* pin = in + (((size_t)b * CIN) * D_ + dd) * HW_ + hh * W_;
      for (int kw = 0; kw < 3; kw++) {
        int ww = w + kw - 1;
        if (ww < 0 || ww >= W_) continue;
#pragma unroll
        for (int ci = 0; ci < CIN; ci++) {
          float v = ldf(pin + (size_t)ci * D_ * HW_ + ww);
          const float* lwp = lw + (ci * 3 + kd) * 9 + kh * 3 + kw;
#pragma unroll
          for (int co = 0; co < COUT; co++) acc[co] += v * lwp[co * CIN * 27];
        }
      }
    }
  }
  size_t obase = (((size_t)b * COUT) * D_ + d) * HW_ + h * W_ + w;
#pragma unroll
  for (int co = 0; co < COUT; co++) {
    float r = acc[co];
    if (HASBIAS) r += bias[co];
    stf(out + obase + (size_t)co * D_ * HW_, r);
  }
}

// ---------------------------------------------------------------------------
// 3x3 conv2d, pad 1; input optionally split (channel concat); optional
// bias and +dsa (final regression conv).
// ---------------------------------------------------------------------------
template <int C0, int C1, int COUT, bool HASBIAS, bool ADD_DSA>
__global__ __launch_bounds__(320)
void conv2d_kernel(const float* __restrict__ in0, const float* __restrict__ in1,
                   const float* __restrict__ wt, const float* __restrict__ bias,
                   const float* __restrict__ dsa, float* __restrict__ out) {
  constexpr int CINT = C0 + C1;
  __shared__ float lw[COUT * CINT * 9];
  for (int i = threadIdx.x; i < COUT * CINT * 9; i += 320) lw[i] = wt[i];
  __syncthreads();
  int w = threadIdx.x;
  int h = blockIdx.x % H_;
  int b = blockIdx.x / H_;
  float acc[COUT];
#pragma unroll
  for (int co = 0; co < COUT; co++) acc[co] = 0.f;
  for (int kh = 0; kh < 3; kh++) {
    int hh = h + kh - 1;
    if (hh < 0 || hh >= H_) continue;
    for (int kw = 0; kw < 3; kw++) {
      int ww = w + kw - 1;
      if (ww < 0 || ww >= W_) continue;
#pragma unroll
      for (int ci = 0; ci < C0; ci++) {
        float v = in0[((size_t)(b * C0 + ci)) * HW_ + hh * W_ + ww];
        const float* lwp = lw + (ci * 3 + kh) * 3 + kw;
#pragma unroll
        for (int co = 0; co < COUT; co++) acc[co] += v * lwp[co * CINT * 9];
      }
      if (C1 > 0) {
#pragma unroll
        for (int ci = 0; ci < (C1 > 0 ? C1 : 1); ci++) {
          float v = in1[((size_t)(b * C1 + ci)) * HW_ + hh * W_ + ww];
          const float* lwp = lw + ((C0 + ci) * 3 + kh) * 3 + kw;
#pragma unroll
          for (int co = 0; co < COUT; co++) acc[co] += v * lwp[co * CINT * 9];
        }
      }
    }
  }
#pragma unroll
  for (int co = 0; co < COUT; co++) {
    float r = acc[co];
    if (HASBIAS) r += bias[co];
    if (ADD_DSA) r += dsa[(size_t)b * HW_ + h * W_ + w];
    out[((size_t)(b * COUT + co)) * HW_ + h * W_ + w] = r;
  }
}

// ---------------------------------------------------------------------------
// Conv1d over flattened H*W axis (k=3, pad 1, 24->24, no bias)
// ---------------------------------------------------------------------------
__global__ __launch_bounds__(256)
void conv1d_kernel(const float* __restrict__ logits, const float* __restrict__ wt,
                   float* __restrict__ out) {
  __shared__ float lw[D_ * D_ * 3];
  for (int i = threadIdx.x; i < D_ * D_ * 3; i += 256) lw[i] = wt[i];
  __syncthreads();
  int idx = blockIdx.x * 256 + threadIdx.x;
  int b = idx / HW_;
  int i = idx % HW_;
  float acc[D_];
#pragma unroll
  for (int o = 0; o < D_; o++) acc[o] = 0.f;
  for (int k = 0; k < 3; k++) {
    int pos = i + k - 1;
    if (pos < 0 || pos >= HW_) continue;
#pragma unroll
    for (int din = 0; din < D_; din++) {
      float v = logits[((size_t)b * D_ + din) * HW_ + pos];
      const float* lwp = lw + din * 3 + k;
#pragma unroll
      for (int o = 0; o < D_; o++) acc[o] += v * lwp[o * D_ * 3];
    }
  }
#pragma unroll
  for (int o = 0; o < D_; o++) out[((size_t)b * D_ + o) * HW_ + i] = acc[o];
}

// ---------------------------------------------------------------------------
// GroupNorm stats: per (b,group) sum/sumsq. One double-atomic pair per block.
// ---------------------------------------------------------------------------
template <typename T>
__global__ __launch_bounds__(256)
void stats_kernel(const T* __restrict__ x, double* __restrict__ stats,
                  int Cc, int chg, size_t per_ch, int nchunk) {
  int tmp = blockIdx.x;
  int chunk = tmp % nchunk; tmp /= nchunk;
  int cig = tmp % chg; tmp /= chg;
  int grp = tmp % 8;
  int b = tmp / 8;
  int c = grp * chg + cig;
  size_t len = per_ch / nchunk;
  const T* p = x + ((size_t)b * Cc + c) * per_ch + (size_t)chunk * len;
  float s = 0.f, s2 = 0.f;
  for (size_t i = threadIdx.x; i < len; i += 256) {
    float v = ldf(p + i);
    s += v;
    s2 += v * v;
  }
  __shared__ double ls[256], ls2[256];
  ls[threadIdx.x] = (double)s;
  ls2[threadIdx.x] = (double)s2;
  __syncthreads();
  for (int off = 128; off > 0; off >>= 1) {
    if (threadIdx.x < off) {
      ls[threadIdx.x] += ls[threadIdx.x + off];
      ls2[threadIdx.x] += ls2[threadIdx.x + off];
    }
    __syncthreads();
  }
  if (threadIdx.x == 0) {
    atomicAdd(&stats[(size_t)(b * 8 + grp) * 2], ls[0]);
    atomicAdd(&stats[(size_t)(b * 8 + grp) * 2 + 1], ls2[0]);
  }
}

// ---------------------------------------------------------------------------
// GroupNorm normalize + SiLU. grid = (nblk, C, B)
// ---------------------------------------------------------------------------
template <typename T>
__global__ __launch_bounds__(256)
void norm_silu_kernel(const T* __restrict__ x, T* __restrict__ y,
                      const double* __restrict__ stats,
                      const float* __restrict__ gamma, const float* __restrict__ beta,
                      int chg, size_t per_ch, double invN) {
  int c = blockIdx.y;
  int b = blockIdx.z;
  int grp = c / chg;
  double s = stats[(size_t)(b * 8 + grp) * 2];
  double s2 = stats[(size_t)(b * 8 + grp) * 2 + 1];
  double mean_d = s * invN;
  double var_d = s2 * invN - mean_d * mean_d;
  float sc = gamma[c] / sqrtf((float)var_d + EPS_);
  float sh = beta[c] - (float)mean_d * sc;
  size_t base = ((size_t)b * gridDim.y + c) * per_ch;
  size_t chunk = (per_ch + gridDim.x - 1) / gridDim.x;
  size_t start = (size_t)blockIdx.x * chunk;
  size_t end = start + chunk;
  if (end > per_ch) end = per_ch;
  for (size_t i = start + threadIdx.x; i < end; i += 256) {
    float v = ldf(x + base + i) * sc + sh;
    stf(y + base + i, v / (1.f + __expf(-v)));
  }
}

// norm+SiLU, fp32-in, fp32-out, separate output (feat head)
__global__ __launch_bounds__(256)
void norm_silu_f32o_kernel(const float* __restrict__ x, float* __restrict__ y,
                           const double* __restrict__ stats,
                           const float* __restrict__ gamma, const float* __restrict__ beta,
                           int chg, size_t per_ch, double invN) {
  int c = blockIdx.y;
  int b = blockIdx.z;
  int grp = c / chg;
  double s = stats[(size_t)(b * 8 + grp) * 2];
  double s2 = stats[(size_t)(b * 8 + grp) * 2 + 1];
  double mean_d = s * invN;
  double var_d = s2 * invN - mean_d * mean_d;
  float sc = gamma[c] / sqrtf((float)var_d + EPS_);
  float sh = beta[c] - (float)mean_d * sc;
  size_t base = ((size_t)b * gridDim.y + c) * per_ch;
  size_t chunk = (per_ch + gridDim.x - 1) / gridDim.x;
  size_t start = (size_t)blockIdx.x * chunk;
  size_t end = start + chunk;
  if (end > per_ch) end = per_ch;
  for (size_t i = start + threadIdx.x; i < end; i += 256) {
    float v = x[base + i] * sc + sh;
    y[base + i] = v / (1.f + __expf(-v));
  }
}

// ---------------------------------------------------------------------------
// Softmax over D + soft-argmin + confidence
// ---------------------------------------------------------------------------
__global__ __launch_bounds__(320)
void softmax_kernel(const float* __restrict__ logits, float* __restrict__ dsa,
                    float* __restrict__ conf) {
  int w = threadIdx.x;
  int h = blockIdx.x % H_;
  int b = blockIdx.x / H_;
  size_t base = ((size_t)b * D_) * HW_ + h * W_ + w;
  float v[D_];
  float m = -1e30f;
#pragma unroll
  for (int d = 0; d < D_; d++) {
    v[d] = logits[base + (size_t)d * HW_];
    m = fmaxf(m, v[d]);
  }
  float s = 0.f, wd = 0.f;
#pragma unroll
  for (int d = 0; d < D_; d++) {
    float e = __expf(v[d] - m);
    s += e;
    wd += (float)d * e;
  }
  float inv = 1.f / s;
  dsa[(size_t)b * HW_ + h * W_ + w] = wd * inv;
  conf[(size_t)b * HW_ + h * W_ + w] = inv;  // max prob
}

// ---------------------------------------------------------------------------
// 3D aggregation chain, templated on big-intermediate storage type
// ---------------------------------------------------------------------------
template <typename T>
static void run_agg(const float* cv, T* a1, T* a2, float* logits, double* stats,
                    const float* agg_w1, const float* agg_g1, const float* agg_b1,
                    const float* agg_w2, const float* agg_g2, const float* agg_b2,
                    const float* agg_w3, const float* agg_bias3, hipStream_t stream) {
  conv3d_kernel<G_, 16, false, float, T><<<B_ * D_ * H_, 320, 0, stream>>>(cv, agg_w1, nullptr, a1);
  stats_kernel<T><<<B_ * 8 * 2 * 32, 256, 0, stream>>>(a1, stats + 0, 16, 2, (size_t)DHW_, 32);
  norm_silu_kernel<T><<<dim3(1200, 16, B_), 256, 0, stream>>>(a1, a1, stats + 0, agg_g1, agg_b1,
                                                              2, (size_t)DHW_, 1.0 / (2.0 * DHW_));
  conv3d_kernel<16, 16, false, T, T><<<B_ * D_ * H_, 320, 0, stream>>>(a1, agg_w2, nullptr, a2);
  stats_kernel<T><<<B_ * 8 * 2 * 32, 256, 0, stream>>>(a2, stats + 32, 16, 2, (size_t)DHW_, 32);
  norm_silu_kernel<T><<<dim3(1200, 16, B_), 256, 0, stream>>>(a2, a2, stats + 32, agg_g2, agg_b2,
                                                              2, (size_t)DHW_, 1.0 / (2.0 * DHW_));
  conv3d_kernel<16, 1, true, T, float><<<B_ * D_ * H_, 320, 0, stream>>>(a2, agg_w3, agg_bias3, logits);
}

extern "C" void kernel_launch(void* const* d_in, const int* in_sizes, int n_in,
                              void* d_out, int out_size, void* d_ws, size_t ws_size,
                              hipStream_t stream) {
  const float* fL = (const float*)d_in[0];
  const float* fR = (const float*)d_in[1];
  const float* agg_w1 = (const float*)d_in[2];
  const float* agg_g1 = (const float*)d_in[3];
  const float* agg_b1 = (const float*)d_in[4];
  const float* agg_w2 = (const float*)d_in[5];
  const float* agg_g2 = (const float*)d_in[6];
  const float* agg_b2 = (const float*)d_in[7];
  const float* agg_w3 = (const float*)d_in[8];
  const float* agg_bias3 = (const float*)d_in[9];
  const float* feat_w = (const float*)d_in[10];
  const float* feat_g = (const float*)d_in[11];
  const float* feat_b = (const float*)d_in[12];
  const float* apc_w = (const float*)d_in[13];
  const float* reg_w1 = (const float*)d_in[14];
  const float* reg_g1 = (const float*)d_in[15];
  const float* reg_b1 = (const float*)d_in[16];
  const float* reg_w2 = (const float*)d_in[17];
  const float* reg_bias2 = (const float*)d_in[18];

  char* wsb = (char*)d_ws;
  constexpr size_t BIG = 39321600;               // B*16*D*HW elements
  const size_t fp32_need = BIG * 8ull + 1024;    // two fp32 big buffers + stats
  bool useF32 = ws_size >= fp32_need;

  // Small fp32 buffers at the base of ws (region is free whenever the big
  // intermediate that lived there is dead).
  float* logits = (float*)wsb;                   // 2,457,600 f
  float* apc = logits + 2457600;                 // 2,457,600 f
  float* h2 = apc + 2457600;                     // 3,276,800 f
  float* dsa = h2 + 3276800;                     //   102,400 f
  float* featraw = dsa + 102400;                 // 1,638,400 f

  float* out = (float*)d_out;
  float* out_dinit = out;                        // [B,1,H,W]
  float* out_sx = out + 102400;                  // zeros (sx, sy)
  float* out_feat = out + 307200;                // [B,16,H,W]
  float* out_conf = out + 1945600;               // [B,1,H,W]

  double* stats;
  if (useF32) stats = (double*)(wsb + BIG * 8ull);
  else        stats = (double*)(wsb + BIG * 4ull);

  hipMemsetAsync(stats, 0, 128 * sizeof(double), stream);
  hipMemsetAsync(out_sx, 0, 2 * 102400 * sizeof(float), stream);

  if (useF32) {
    // layout: [a1: BIG f32][a2: BIG f32 (cv overlays, dead before a2)][stats]
    float* a1 = (float*)wsb;
    float* a2 = (float*)(wsb + BIG * 4ull);
    float* cv = a2;
    cv_kernel<<<dim3(B_ * H_, G_), 320, 0, stream>>>(fL, fR, cv);
    run_agg<float>(cv, a1, a2, logits, stats, agg_w1, agg_g1, agg_b1,
                   agg_w2, agg_g2, agg_b2, agg_w3, agg_bias3, stream);
  } else {
    // layout: [a1: BIG bf16][cv f32 -> a2 bf16][stats]   (157.3 MB peak)
    __hip_bfloat16* a1 = (__hip_bfloat16*)wsb;
    __hip_bfloat16* a2 = (__hip_bfloat16*)(wsb + BIG * 2ull);
    float* cv = (float*)(wsb + BIG * 2ull);
    cv_kernel<<<dim3(B_ * H_, G_), 320, 0, stream>>>(fL, fR, cv);
    run_agg<__hip_bfloat16>(cv, a1, a2, logits, stats, agg_w1, agg_g1, agg_b1,
                            agg_w2, agg_g2, agg_b2, agg_w3, agg_bias3, stream);
  }

  // softmax -> dsa (ws), conf (out)
  softmax_kernel<<<B_ * H_, 320, 0, stream>>>(logits, dsa, out_conf);

  // feat head: conv2d(64->16) ; GN ; SiLU -> out_feat
  conv2d_kernel<C_, 0, 16, false, false><<<B_ * H_, 320, 0, stream>>>(
      fL, nullptr, feat_w, nullptr, nullptr, featraw);
  stats_kernel<float><<<B_ * 8 * 2 * 8, 256, 0, stream>>>(featraw, stats + 64, 16, 2, (size_t)HW_, 8);
  norm_silu_f32o_kernel<<<dim3(50, 16, B_), 256, 0, stream>>>(featraw, out_feat, stats + 64,
                                                              feat_g, feat_b, 2, (size_t)HW_,
                                                              1.0 / (2.0 * HW_));

  // apc conv1d on flattened logits
  conv1d_kernel<<<(B_ * HW_) / 256, 256, 0, stream>>>(logits, apc_w, apc);

  // regression head conv1 (24+16 -> 32) ; GN ; SiLU
  conv2d_kernel<D_, 16, 32, false, false><<<B_ * H_, 320, 0, stream>>>(
      apc, out_feat, reg_w1, nullptr, nullptr, h2);
  stats_kernel<float><<<B_ * 8 * 4 * 8, 256, 0, stream>>>(h2, stats + 96, 32, 4, (size_t)HW_, 8);
  norm_silu_f32o_kernel<<<dim3(50, 32, B_), 256, 0, stream>>>(h2, h2, stats + 96, reg_g1, reg_b1,
                                                              4, (size_t)HW_, 1.0 / (4.0 * HW_));

  // regression conv2 (32->1) + bias + d_sa -> d_init
  conv2d_kernel<32, 0, 1, true, true><<<B_ * H_, 320, 0, stream>>>(
      h2, nullptr, reg_w2, reg_bias2, dsa, out_dinit);
}

// Round 6
// 1321.135 us; speedup vs baseline: 1.9592x; 1.9592x over previous
//
#include <hip/hip_runtime.h>
#include <hip/hip_bf16.h>
#include <math.h>

// Problem constants
constexpr int B_ = 2;
constexpr int C_ = 64;
constexpr int H_ = 160;
constexpr int W_ = 320;
constexpr int G_ = 8;       // correlation groups
constexpr int D_ = 24;      // max disparity
constexpr int HW_ = H_ * W_;        // 51200
constexpr int DHW_ = D_ * HW_;      // 1228800
constexpr float EPS_ = 1e-5f;

typedef __bf16 b8 __attribute__((ext_vector_type(8)));
typedef float  f4 __attribute__((ext_vector_type(4)));

__device__ inline float bf_lo(unsigned u) { return __builtin_bit_cast(float, u << 16); }
__device__ inline float bf_hi(unsigned u) { return __builtin_bit_cast(float, u & 0xffff0000u); }
__device__ inline unsigned pack2(float a, float b) {
  unsigned lo = __builtin_bit_cast(unsigned short, (__bf16)a);
  unsigned hi = __builtin_bit_cast(unsigned short, (__bf16)b);
  return (hi << 16) | lo;
}
__device__ inline float silu(float v) { return v / (1.f + __expf(-v)); }

// ---------------------------------------------------------------------------
// Cost volume, channels-last bf16: cv[b,d,h,w,g] = mean_c fL[g*8+c]*fR[g*8+c] shifted
// ---------------------------------------------------------------------------
__global__ __launch_bounds__(320)
void cv_cl_kernel(const float* __restrict__ fL, const float* __restrict__ fR,
                  __bf16* __restrict__ cv) {
  int w = threadIdx.x;
  int h = blockIdx.x % H_;
  int b = blockIdx.x / H_;
  int d0 = blockIdx.y * 6;
  const size_t rowbase = ((size_t)(b * C_) * H_ + h) * W_;
  float l[C_];
#pragma unroll
  for (int c = 0; c < C_; c++) l[c] = fL[rowbase + (size_t)c * HW_ + w];
  for (int dd = 0; dd < 6; dd++) {
    int d = d0 + dd;
    float s[8] = {0.f,0.f,0.f,0.f,0.f,0.f,0.f,0.f};
    if (w >= d) {
      const float* pr = fR + rowbase + (w - d);
#pragma unroll
      for (int c = 0; c < C_; c++) s[c >> 3] += l[c] * pr[(size_t)c * HW_];
    }
    b8 r;
#pragma unroll
    for (int g = 0; g < 8; g++) r[g] = (__bf16)(s[g] * 0.125f);
    *(b8*)(cv + ((size_t)((b * D_ + d) * H_ + h) * W_ + w) * 8) = r;
  }
}

// ---------------------------------------------------------------------------
// Weight prep: per-lane MFMA B-fragments. K order = taps x ci (ci fastest).
// wf[p][lane][j] = W[k=(lane>>4)*8+j of K-tile p][co=lane&15]; taps>26 -> 0.
// ---------------------------------------------------------------------------
__global__ void wprep_kernel(const float* __restrict__ w1, const float* __restrict__ w2,
                             __bf16* __restrict__ wf1, __bf16* __restrict__ wf2) {
  int lane = threadIdx.x;      // 64 threads
  int co = lane & 15, kb = lane >> 4;
#pragma unroll
  for (int p = 0; p < 7; p++)
#pragma unroll
    for (int j = 0; j < 8; j++) {
      int kl = kb * 8 + j;
      int tap = p * 4 + (kl >> 3);
      int ci = kl & 7;
      float v = (tap <= 26) ? w1[(co * 8 + ci) * 27 + tap] : 0.f;
      wf1[(p * 64 + lane) * 8 + j] = (__bf16)v;
    }
#pragma unroll
  for (int p = 0; p < 14; p++)
#pragma unroll
    for (int j = 0; j < 8; j++) {
      int kl = kb * 8 + j;
      int tap = p * 2 + (kl >> 4);
      int ci = kl & 15;
      float v = (tap <= 26) ? w2[(co * 16 + ci) * 27 + tap] : 0.f;
      wf2[(p * 64 + lane) * 8 + j] = (__bf16)v;
    }
}

// ---------------------------------------------------------------------------
// 3x3x3 conv3d as implicit-GEMM MFMA. Channels-last bf16 in/out (out: 16 ch).
// Block 256 = 4 waves; block = (b,d,h); each wave does 5 M-tiles of 16 w's.
// ---------------------------------------------------------------------------
template <int CIN, int PAIRS>
__global__ __launch_bounds__(256)
void conv3d_mfma_kernel(const __bf16* __restrict__ in, const __bf16* __restrict__ wf,
                        __bf16* __restrict__ out) {
  const int lane = threadIdx.x & 63;
  const int wid = threadIdx.x >> 6;
  const int bid = blockIdx.x;              // (b*24+d)*160 + h
  const int h = bid % H_;
  const int d = (bid / H_) % D_;
  const int m = lane & 15;
  const int tpp = 32 / CIN;                // taps per K-tile
  const int tapsel = (CIN == 16) ? (lane >> 5) : (lane >> 4);
  const int ci0 = (CIN == 16) ? ((lane >> 1) & 8) : 0;
  b8 wfr[PAIRS];
#pragma unroll
  for (int p = 0; p < PAIRS; p++) wfr[p] = *(const b8*)(wf + (p * 64 + lane) * 8);
  int poff[PAIRS], dwv[PAIRS];
  bool vdh[PAIRS];
#pragma unroll
  for (int p = 0; p < PAIRS; p++) {
    int tap = p * tpp + tapsel;
    if (tap > 26) tap = 26;                // dummy half has zero weights
    int kd = tap / 9, kh = (tap / 3) % 3, kw = tap % 3;
    poff[p] = (kd - 1) * HW_ + (kh - 1) * W_ + (kw - 1);
    dwv[p] = kw - 1;
    vdh[p] = ((unsigned)(d + kd - 1) < (unsigned)D_) &&
             ((unsigned)(h + kh - 1) < (unsigned)H_);
  }
  const int pos0row = bid * W_;
  for (int t = 0; t < 5; t++) {
    const int w0 = (wid * 5 + t) * 16;
    const int pos0 = pos0row + w0;
    f4 acc = {0.f, 0.f, 0.f, 0.f};
#pragma unroll
    for (int p = 0; p < PAIRS; p++) {
      b8 a = {};
      if (vdh[p] && ((unsigned)(w0 + m + dwv[p]) < (unsigned)W_))
        a = *(const b8*)(in + (long)(pos0 + m + poff[p]) * CIN + ci0);
      acc = __builtin_amdgcn_mfma_f32_16x16x32_bf16(a, wfr[p], acc, 0, 0, 0);
    }
    const int co = lane & 15;
    const int r0 = (lane >> 4) * 4;
#pragma unroll
    for (int r = 0; r < 4; r++)
      out[(size_t)(pos0 + r0 + r) * 16 + co] = (__bf16)acc[r];
  }
}

// ---------------------------------------------------------------------------
// GN stats, channels-last bf16 [b][pos][16]: per (b,group of 2 ch) sum/sumsq
// ---------------------------------------------------------------------------
__global__ __launch_bounds__(256)
void stats_cl_kernel(const __bf16* __restrict__ x, double* __restrict__ st) {
  int b = blockIdx.y;
  float sg[8] = {0,0,0,0,0,0,0,0}, sq[8] = {0,0,0,0,0,0,0,0};
  for (int i = blockIdx.x * 256 + threadIdx.x; i < DHW_; i += gridDim.x * 256) {
    const uint4* p = (const uint4*)(x + ((size_t)b * DHW_ + i) * 16);
    uint4 q0 = p[0], q1 = p[1];
    unsigned us[8] = {q0.x, q0.y, q0.z, q0.w, q1.x, q1.y, q1.z, q1.w};
#pragma unroll
    for (int k = 0; k < 8; k++) {
      float v0 = bf_lo(us[k]), v1 = bf_hi(us[k]);
      sg[k] += v0 + v1;
      sq[k] += v0 * v0 + v1 * v1;
    }
  }
#pragma unroll
  for (int k = 0; k < 8; k++)
    for (int off = 32; off; off >>= 1) {
      sg[k] += __shfl_xor(sg[k], off, 64);
      sq[k] += __shfl_xor(sq[k], off, 64);
    }
  __shared__ float ls[4][16];
  int wid = threadIdx.x >> 6, lane = threadIdx.x & 63;
  if (lane == 0) {
#pragma unroll
    for (int k = 0; k < 8; k++) { ls[wid][k] = sg[k]; ls[wid][8 + k] = sq[k]; }
  }
  __syncthreads();
  if (threadIdx.x < 16) {
    float t = ls[0][threadIdx.x] + ls[1][threadIdx.x] + ls[2][threadIdx.x] + ls[3][threadIdx.x];
    int g = threadIdx.x & 7, which = threadIdx.x >> 3;
    atomicAdd(&st[(size_t)(b * 8 + g) * 2 + which], (double)t);
  }
}

// ---------------------------------------------------------------------------
// GN normalize + SiLU in place, channels-last bf16 (16 ch, 8 groups of 2)
// ---------------------------------------------------------------------------
__global__ __launch_bounds__(256)
void norm_cl_kernel(__bf16* __restrict__ x, const double* __restrict__ st,
                    const float* __restrict__ gamma, const float* __restrict__ beta,
                    double invN) {
  int b = blockIdx.y;
  __shared__ float scs[16], shs[16];
  if (threadIdx.x < 16) {
    int c = threadIdx.x, grp = c >> 1;
    double mean = st[(size_t)(b * 8 + grp) * 2] * invN;
    double var = st[(size_t)(b * 8 + grp) * 2 + 1] * invN - mean * mean;
    float sc = gamma[c] * rsqrtf((float)var + EPS_);
    scs[c] = sc;
    shs[c] = beta[c] - (float)mean * sc;
  }
  __syncthreads();
  float sc[16], sh[16];
#pragma unroll
  for (int c = 0; c < 16; c++) { sc[c] = scs[c]; sh[c] = shs[c]; }
  for (int i = blockIdx.x * 256 + threadIdx.x; i < DHW_; i += gridDim.x * 256) {
    uint4* p = (uint4*)(x + ((size_t)b * DHW_ + i) * 16);
    uint4 q0 = p[0], q1 = p[1];
    unsigned us[8] = {q0.x, q0.y, q0.z, q0.w, q1.x, q1.y, q1.z, q1.w};
    unsigned ro[8];
#pragma unroll
    for (int k = 0; k < 8; k++) {
      int c0 = 2 * k;
      float v0 = silu(bf_lo(us[k]) * sc[c0] + sh[c0]);
      float v1 = silu(bf_hi(us[k]) * sc[c0 + 1] + sh[c0 + 1]);
      ro[k] = pack2(v0, v1);
    }
    p[0] = make_uint4(ro[0], ro[1], ro[2], ro[3]);
    p[1] = make_uint4(ro[4], ro[5], ro[6], ro[7]);
  }
}

// ---------------------------------------------------------------------------
// conv3d #3 (16->1) + bias, channels-last bf16 input -> fp32 logits [B,D,H,W]
// ---------------------------------------------------------------------------
__global__ __launch_bounds__(256)
void conv3_cl_kernel(const __bf16* __restrict__ a2, const float* __restrict__ wt,
                     const float* __restrict__ bias, float* __restrict__ logits) {
  __shared__ float lw[432];
  for (int i = threadIdx.x; i < 432; i += 256) {
    int tap = i / 16, ci = i % 16;
    lw[i] = wt[ci * 27 + tap];
  }
  __syncthreads();
  float bv = bias[0];
  const int total = B_ * DHW_;
  for (int pos = blockIdx.x * 256 + threadIdx.x; pos < total; pos += gridDim.x * 256) {
    int w = pos % W_;
    int h = (pos / W_) % H_;
    int d = (pos / HW_) % D_;
    float s = bv;
#pragma unroll
    for (int tap = 0; tap < 27; tap++) {
      const int kd = tap / 9, kh = (tap / 3) % 3, kw = tap % 3;
      if ((unsigned)(d + kd - 1) < (unsigned)D_ && (unsigned)(h + kh - 1) < (unsigned)H_ &&
          (unsigned)(w + kw - 1) < (unsigned)W_) {
        const __bf16* p = a2 + ((long)pos + (kd - 1) * HW_ + (kh - 1) * W_ + (kw - 1)) * 16;
        uint4 q0 = *(const uint4*)p;
        uint4 q1 = *(const uint4*)(p + 8);
        const float* lp = lw + tap * 16;
        s += bf_lo(q0.x) * lp[0] + bf_hi(q0.x) * lp[1] + bf_lo(q0.y) * lp[2] + bf_hi(q0.y) * lp[3] +
             bf_lo(q0.z) * lp[4] + bf_hi(q0.z) * lp[5] + bf_lo(q0.w) * lp[6] + bf_hi(q0.w) * lp[7] +
             bf_lo(q1.x) * lp[8] + bf_hi(q1.x) * lp[9] + bf_lo(q1.y) * lp[10] + bf_hi(q1.y) * lp[11] +
             bf_lo(q1.z) * lp[12] + bf_hi(q1.z) * lp[13] + bf_lo(q1.w) * lp[14] + bf_hi(q1.w) * lp[15];
      }
    }
    logits[pos] = s;
  }
}

// ---------------------------------------------------------------------------
// 3x3 conv2d, pad 1 (heads; unchanged, fp32 channels-first)
// ---------------------------------------------------------------------------
template <int C0, int C1, int COUT, bool HASBIAS, bool ADD_DSA>
__global__ __launch_bounds__(320)
void conv2d_kernel(const float* __restrict__ in0, const float* __restrict__ in1,
                   const float* __restrict__ wt, const float* __restrict__ bias,
                   const float* __restrict__ dsa, float* __restrict__ out) {
  constexpr int CINT = C0 + C1;
  __shared__ float lw[COUT * CINT * 9];
  for (int i = threadIdx.x; i < COUT * CINT * 9; i += 320) lw[i] = wt[i];
  __syncthreads();
  int w = threadIdx.x;
  int h = blockIdx.x % H_;
  int b = blockIdx.x / H_;
  float acc[COUT];
#pragma unroll
  for (int co = 0; co < COUT; co++) acc[co] = 0.f;
  for (int kh = 0; kh < 3; kh++) {
    int hh = h + kh - 1;
    if (hh < 0 || hh >= H_) continue;
    for (int kw = 0; kw < 3; kw++) {
      int ww = w + kw - 1;
      if (ww < 0 || ww >= W_) continue;
#pragma unroll
      for (int ci = 0; ci < C0; ci++) {
        float v = in0[((size_t)(b * C0 + ci)) * HW_ + hh * W_ + ww];
        const float* lwp = lw + (ci * 3 + kh) * 3 + kw;
#pragma unroll
        for (int co = 0; co < COUT; co++) acc[co] += v * lwp[co * CINT * 9];
      }
      if (C1 > 0) {
#pragma unroll
        for (int ci = 0; ci < (C1 > 0 ? C1 : 1); ci++) {
          float v = in1[((size_t)(b * C1 + ci)) * HW_ + hh * W_ + ww];
          const float* lwp = lw + ((C0 + ci) * 3 + kh) * 3 + kw;
#pragma unroll
          for (int co = 0; co < COUT; co++) acc[co] += v * lwp[co * CINT * 9];
        }
      }
    }
  }
#pragma unroll
  for (int co = 0; co < COUT; co++) {
    float r = acc[co];
    if (HASBIAS) r += bias[co];
    if (ADD_DSA) r += dsa[(size_t)b * HW_ + h * W_ + w];
    out[((size_t)(b * COUT + co)) * HW_ + h * W_ + w] = r;
  }
}

// ---------------------------------------------------------------------------
// Conv1d over flattened H*W axis (k=3, pad 1, 24->24, no bias) — unchanged
// ---------------------------------------------------------------------------
__global__ __launch_bounds__(256)
void conv1d_kernel(const float* __restrict__ logits, const float* __restrict__ wt,
                   float* __restrict__ out) {
  __shared__ float lw[D_ * D_ * 3];
  for (int i = threadIdx.x; i < D_ * D_ * 3; i += 256) lw[i] = wt[i];
  __syncthreads();
  int idx = blockIdx.x * 256 + threadIdx.x;
  int b = idx / HW_;
  int i = idx % HW_;
  float acc[D_];
#pragma unroll
  for (int o = 0; o < D_; o++) acc[o] = 0.f;
  for (int k = 0; k < 3; k++) {
    int pos = i + k - 1;
    if (pos < 0 || pos >= HW_) continue;
#pragma unroll
    for (int din = 0; din < D_; din++) {
      float v = logits[((size_t)b * D_ + din) * HW_ + pos];
      const float* lwp = lw + din * 3 + k;
#pragma unroll
      for (int o = 0; o < D_; o++) acc[o] += v * lwp[o * D_ * 3];
    }
  }
#pragma unroll
  for (int o = 0; o < D_; o++) out[((size_t)b * D_ + o) * HW_ + i] = acc[o];
}

// ---------------------------------------------------------------------------
// GN stats fp32 channels-first (heads) — unchanged
// ---------------------------------------------------------------------------
__global__ __launch_bounds__(256)
void stats_kernel(const float* __restrict__ x, double* __restrict__ stats,
                  int Cc, int chg, size_t per_ch, int nchunk) {
  int tmp = blockIdx.x;
  int chunk = tmp % nchunk; tmp /= nchunk;
  int cig = tmp % chg; tmp /= chg;
  int grp = tmp % 8;
  int b = tmp / 8;
  int c = grp * chg + cig;
  size_t len = per_ch / nchunk;
  const float* p = x + ((size_t)b * Cc + c) * per_ch + (size_t)chunk * len;
  float s = 0.f, s2 = 0.f;
  for (size_t i = threadIdx.x; i < len; i += 256) {
    float v = p[i];
    s += v;
    s2 += v * v;
  }
  __shared__ double ls[256], ls2[256];
  ls[threadIdx.x] = (double)s;
  ls2[threadIdx.x] = (double)s2;
  __syncthreads();
  for (int off = 128; off > 0; off >>= 1) {
    if (threadIdx.x < off) {
      ls[threadIdx.x] += ls[threadIdx.x + off];
      ls2[threadIdx.x] += ls2[threadIdx.x + off];
    }
    __syncthreads();
  }
  if (threadIdx.x == 0) {
    atomicAdd(&stats[(size_t)(b * 8 + grp) * 2], ls[0]);
    atomicAdd(&stats[(size_t)(b * 8 + grp) * 2 + 1], ls2[0]);
  }
}

// norm+SiLU fp32 channels-first (heads) — unchanged
__global__ __launch_bounds__(256)
void norm_silu_f32o_kernel(const float* __restrict__ x, float* __restrict__ y,
                           const double* __restrict__ stats,
                           const float* __restrict__ gamma, const float* __restrict__ beta,
                           int chg, size_t per_ch, double invN) {
  int c = blockIdx.y;
  int b = blockIdx.z;
  int grp = c / chg;
  double s = stats[(size_t)(b * 8 + grp) * 2];
  double s2 = stats[(size_t)(b * 8 + grp) * 2 + 1];
  double mean_d = s * invN;
  double var_d = s2 * invN - mean_d * mean_d;
  float sc = gamma[c] / sqrtf((float)var_d + EPS_);
  float sh = beta[c] - (float)mean_d * sc;
  size_t base = ((size_t)b * gridDim.y + c) * per_ch;
  size_t chunk = (per_ch + gridDim.x - 1) / gridDim.x;
  size_t start = (size_t)blockIdx.x * chunk;
  size_t end = start + chunk;
  if (end > per_ch) end = per_ch;
  for (size_t i = start + threadIdx.x; i < end; i += 256) {
    float v = x[base + i] * sc + sh;
    y[base + i] = v / (1.f + __expf(-v));
  }
}

// ---------------------------------------------------------------------------
// Softmax over D + soft-argmin + confidence — unchanged
// ---------------------------------------------------------------------------
__global__ __launch_bounds__(320)
void softmax_kernel(const float* __restrict__ logits, float* __restrict__ dsa,
                    float* __restrict__ conf) {
  int w = threadIdx.x;
  int h = blockIdx.x % H_;
  int b = blockIdx.x / H_;
  size_t base = ((size_t)b * D_) * HW_ + h * W_ + w;
  float v[D_];
  float m = -1e30f;
#pragma unroll
  for (int d = 0; d < D_; d++) {
    v[d] = logits[base + (size_t)d * HW_];
    m = fmaxf(m, v[d]);
  }
  float s = 0.f, wd = 0.f;
#pragma unroll
  for (int d = 0; d < D_; d++) {
    float e = __expf(v[d] - m);
    s += e;
    wd += (float)d * e;
  }
  float inv = 1.f / s;
  dsa[(size_t)b * HW_ + h * W_ + w] = wd * inv;
  conf[(size_t)b * HW_ + h * W_ + w] = inv;  // max prob
}

// ---------------------------------------------------------------------------

extern "C" void kernel_launch(void* const* d_in, const int* in_sizes, int n_in,
                              void* d_out, int out_size, void* d_ws, size_t ws_size,
                              hipStream_t stream) {
  const float* fL = (const float*)d_in[0];
  const float* fR = (const float*)d_in[1];
  const float* agg_w1 = (const float*)d_in[2];
  const float* agg_g1 = (const float*)d_in[3];
  const float* agg_b1 = (const float*)d_in[4];
  const float* agg_w2 = (const float*)d_in[5];
  const float* agg_g2 = (const float*)d_in[6];
  const float* agg_b2 = (const float*)d_in[7];
  const float* agg_w3 = (const float*)d_in[8];
  const float* agg_bias3 = (const float*)d_in[9];
  const float* feat_w = (const float*)d_in[10];
  const float* feat_g = (const float*)d_in[11];
  const float* feat_b = (const float*)d_in[12];
  const float* apc_w = (const float*)d_in[13];
  const float* reg_w1 = (const float*)d_in[14];
  const float* reg_g1 = (const float*)d_in[15];
  const float* reg_b1 = (const float*)d_in[16];
  const float* reg_w2 = (const float*)d_in[17];
  const float* reg_bias2 = (const float*)d_in[18];

  char* wsb = (char*)d_ws;
  // Region A [0, 78.6MB): a1 (bf16 channels-last). After conv2, reused for
  // the small fp32 buffers. Region B [78.6MB, 157.3MB): cv (first 39.3MB),
  // then a2 overlays the whole region (cv dead by then). Tail: wfrags+stats.
  constexpr size_t REG = 78643200ull;            // bytes per region
  __bf16* a1 = (__bf16*)wsb;
  __bf16* cvb = (__bf16*)(wsb + REG);
  __bf16* a2 = (__bf16*)(wsb + REG);
  float* logits = (float*)wsb;                   // 2,457,600 f
  float* apc = logits + 2457600;                 // 2,457,600 f
  float* h2 = apc + 2457600;                     // 3,276,800 f
  float* dsa = h2 + 3276800;                     //   102,400 f
  float* featraw = dsa + 102400;                 // 1,638,400 f  (ends ~39.7MB)
  __bf16* wf1 = (__bf16*)(wsb + 2 * REG);        // 7*64*8 = 3584 elems
  __bf16* wf2 = wf1 + 3584;                      // 14*64*8 = 7168 elems
  double* stats = (double*)(wsb + 2 * REG + 21504);  // 128 doubles

  float* out = (float*)d_out;
  float* out_dinit = out;                        // [B,1,H,W]
  float* out_sx = out + 102400;                  // zeros (sx, sy)
  float* out_feat = out + 307200;                // [B,16,H,W]
  float* out_conf = out + 1945600;               // [B,1,H,W]

  hipMemsetAsync(stats, 0, 128 * sizeof(double), stream);
  hipMemsetAsync(out_sx, 0, 2 * 102400 * sizeof(float), stream);

  // weight fragments
  wprep_kernel<<<1, 64, 0, stream>>>(agg_w1, agg_w2, wf1, wf2);

  // cost volume (channels-last bf16)
  cv_cl_kernel<<<dim3(B_ * H_, 4), 320, 0, stream>>>(fL, fR, cvb);

  // agg conv1 (8->16) MFMA ; GN ; SiLU
  conv3d_mfma_kernel<8, 7><<<B_ * D_ * H_, 256, 0, stream>>>(cvb, wf1, a1);
  stats_cl_kernel<<<dim3(256, B_), 256, 0, stream>>>(a1, stats + 0);
  norm_cl_kernel<<<dim3(512, B_), 256, 0, stream>>>(a1, stats + 0, agg_g1, agg_b1,
                                                    1.0 / (2.0 * DHW_));

  // agg conv2 (16->16) MFMA ; GN ; SiLU
  conv3d_mfma_kernel<16, 14><<<B_ * D_ * H_, 256, 0, stream>>>(a1, wf2, a2);
  stats_cl_kernel<<<dim3(256, B_), 256, 0, stream>>>(a2, stats + 32);
  norm_cl_kernel<<<dim3(512, B_), 256, 0, stream>>>(a2, stats + 32, agg_g2, agg_b2,
                                                    1.0 / (2.0 * DHW_));

  // agg conv3 (16->1) + bias -> logits (fp32, [B,D,H,W])
  conv3_cl_kernel<<<1024, 256, 0, stream>>>(a2, agg_w3, agg_bias3, logits);

  // softmax -> dsa (ws), conf (out)
  softmax_kernel<<<B_ * H_, 320, 0, stream>>>(logits, dsa, out_conf);

  // feat head: conv2d(64->16) ; GN ; SiLU -> out_feat
  conv2d_kernel<C_, 0, 16, false, false><<<B_ * H_, 320, 0, stream>>>(
      fL, nullptr, feat_w, nullptr, nullptr, featraw);
  stats_kernel<<<B_ * 8 * 2 * 8, 256, 0, stream>>>(featraw, stats + 64, 16, 2, (size_t)HW_, 8);
  norm_silu_f32o_kernel<<<dim3(50, 16, B_), 256, 0, stream>>>(featraw, out_feat, stats + 64,
                                                              feat_g, feat_b, 2, (size_t)HW_,
                                                              1.0 / (2.0 * HW_));

  // apc conv1d on flattened logits
  conv1d_kernel<<<(B_ * HW_) / 256, 256, 0, stream>>>(logits, apc_w, apc);

  // regression head conv1 (24+16 -> 32) ; GN ; SiLU
  conv2d_kernel<D_, 16, 32, false, false><<<B_ * H_, 320, 0, stream>>>(
      apc, out_feat, reg_w1, nullptr, nullptr, h2);
  stats_kernel<<<B_ * 8 * 4 * 8, 256, 0, stream>>>(h2, stats + 96, 32, 4, (size_t)HW_, 8);
  norm_silu_f32o_kernel<<<dim3(50, 32, B_), 256, 0, stream>>>(h2, h2, stats + 96, reg_g1, reg_b1,
                                                              4, (size_t)HW_, 1.0 / (4.0 * HW_));

  // regression conv2 (32->1) + bias + d_sa -> d_init
  conv2d_kernel<32, 0, 1, true, true><<<B_ * H_, 320, 0, stream>>>(
      h2, nullptr, reg_w2, reg_bias2, dsa, out_dinit);
}

// Round 9
// 1087.111 us; speedup vs baseline: 2.3810x; 1.2153x over previous
//
#include <hip/hip_runtime.h>
#include <hip/hip_bf16.h>
#include <math.h>

// Problem constants
constexpr int B_ = 2;
constexpr int C_ = 64;
constexpr int H_ = 160;
constexpr int W_ = 320;
constexpr int G_ = 8;       // correlation groups
constexpr int D_ = 24;      // max disparity
constexpr int HW_ = H_ * W_;        // 51200
constexpr int DHW_ = D_ * HW_;      // 1228800
constexpr float EPS_ = 1e-5f;

typedef __bf16 b8 __attribute__((ext_vector_type(8)));
typedef float  f4 __attribute__((ext_vector_type(4)));

__device__ inline float bf_lo(unsigned u) { return __builtin_bit_cast(float, u << 16); }
__device__ inline float bf_hi(unsigned u) { return __builtin_bit_cast(float, u & 0xffff0000u); }
__device__ inline unsigned pack2(float a, float b) {
  unsigned lo = __builtin_bit_cast(unsigned short, (__bf16)a);
  unsigned hi = __builtin_bit_cast(unsigned short, (__bf16)b);
  return (hi << 16) | lo;
}
__device__ inline float silu(float v) { return v / (1.f + __expf(-v)); }

// ---------------------------------------------------------------------------
// Cost volume, channels-last bf16: cv[b,d,h,w,g] = mean_c fL[g*8+c]*fR[g*8+c] shifted
// ---------------------------------------------------------------------------
__global__ __launch_bounds__(320)
void cv_cl_kernel(const float* __restrict__ fL, const float* __restrict__ fR,
                  __bf16* __restrict__ cv) {
  int w = threadIdx.x;
  int h = blockIdx.x % H_;
  int b = blockIdx.x / H_;
  int d0 = blockIdx.y * 6;
  const size_t rowbase = ((size_t)(b * C_) * H_ + h) * W_;
  float l[C_];
#pragma unroll
  for (int c = 0; c < C_; c++) l[c] = fL[rowbase + (size_t)c * HW_ + w];
  for (int dd = 0; dd < 6; dd++) {
    int d = d0 + dd;
    float s[8] = {0.f,0.f,0.f,0.f,0.f,0.f,0.f,0.f};
    if (w >= d) {
      const float* pr = fR + rowbase + (w - d);
#pragma unroll
      for (int c = 0; c < C_; c++) s[c >> 3] += l[c] * pr[(size_t)c * HW_];
    }
    b8 r;
#pragma unroll
    for (int g = 0; g < 8; g++) r[g] = (__bf16)(s[g] * 0.125f);
    *(b8*)(cv + ((size_t)((b * D_ + d) * H_ + h) * W_ + w) * 8) = r;
  }
}

// ---------------------------------------------------------------------------
// Weight prep: per-lane MFMA B-fragments. K order = taps x ci (ci fastest).
// ---------------------------------------------------------------------------
__global__ void wprep_kernel(const float* __restrict__ w1, const float* __restrict__ w2,
                             __bf16* __restrict__ wf1, __bf16* __restrict__ wf2) {
  int lane = threadIdx.x;      // 64 threads
  int co = lane & 15, kb = lane >> 4;
#pragma unroll
  for (int p = 0; p < 7; p++)
#pragma unroll
    for (int j = 0; j < 8; j++) {
      int kl = kb * 8 + j;
      int tap = p * 4 + (kl >> 3);
      int ci = kl & 7;
      float v = (tap <= 26) ? w1[(co * 8 + ci) * 27 + tap] : 0.f;
      wf1[(p * 64 + lane) * 8 + j] = (__bf16)v;
    }
#pragma unroll
  for (int p = 0; p < 14; p++)
#pragma unroll
    for (int j = 0; j < 8; j++) {
      int kl = kb * 8 + j;
      int tap = p * 2 + (kl >> 4);
      int ci = kl & 15;
      float v = (tap <= 26) ? w2[(co * 16 + ci) * 27 + tap] : 0.f;
      wf2[(p * 64 + lane) * 8 + j] = (__bf16)v;
    }
}

// ---------------------------------------------------------------------------
// 3x3x3 conv3d as implicit-GEMM MFMA. Channels-last bf16 in/out (out: 16 ch).
// ---------------------------------------------------------------------------
template <int CIN, int PAIRS>
__global__ __launch_bounds__(256)
void conv3d_mfma_kernel(const __bf16* __restrict__ in, const __bf16* __restrict__ wf,
                        __bf16* __restrict__ out) {
  const int lane = threadIdx.x & 63;
  const int wid = threadIdx.x >> 6;
  const int bid = blockIdx.x;              // (b*24+d)*160 + h
  const int h = bid % H_;
  const int d = (bid / H_) % D_;
  const int m = lane & 15;
  const int tpp = 32 / CIN;                // taps per K-tile
  const int tapsel = (CIN == 16) ? (lane >> 5) : (lane >> 4);
  const int ci0 = (CIN == 16) ? ((lane >> 1) & 8) : 0;
  b8 wfr[PAIRS];
#pragma unroll
  for (int p = 0; p < PAIRS; p++) wfr[p] = *(const b8*)(wf + (p * 64 + lane) * 8);
  int poff[PAIRS], dwv[PAIRS];
  bool vdh[PAIRS];
#pragma unroll
  for (int p = 0; p < PAIRS; p++) {
    int tap = p * tpp + tapsel;
    if (tap > 26) tap = 26;                // dummy half has zero weights
    int kd = tap / 9, kh = (tap / 3) % 3, kw = tap % 3;
    poff[p] = (kd - 1) * HW_ + (kh - 1) * W_ + (kw - 1);
    dwv[p] = kw - 1;
    vdh[p] = ((unsigned)(d + kd - 1) < (unsigned)D_) &&
             ((unsigned)(h + kh - 1) < (unsigned)H_);
  }
  const int pos0row = bid * W_;
  for (int t = 0; t < 5; t++) {
    const int w0 = (wid * 5 + t) * 16;
    const int pos0 = pos0row + w0;
    f4 acc = {0.f, 0.f, 0.f, 0.f};
#pragma unroll
    for (int p = 0; p < PAIRS; p++) {
      b8 a = {};
      if (vdh[p] && ((unsigned)(w0 + m + dwv[p]) < (unsigned)W_))
        a = *(const b8*)(in + (long)(pos0 + m + poff[p]) * CIN + ci0);
      acc = __builtin_amdgcn_mfma_f32_16x16x32_bf16(a, wfr[p], acc, 0, 0, 0);
    }
    const int co = lane & 15;
    const int r0 = (lane >> 4) * 4;
#pragma unroll
    for (int r = 0; r < 4; r++)
      out[(size_t)(pos0 + r0 + r) * 16 + co] = (__bf16)acc[r];
  }
}

// ---------------------------------------------------------------------------
// GN stats, channels-last bf16 [b][pos][16]
// ---------------------------------------------------------------------------
__global__ __launch_bounds__(256)
void stats_cl_kernel(const __bf16* __restrict__ x, double* __restrict__ st) {
  int b = blockIdx.y;
  float sg[8] = {0,0,0,0,0,0,0,0}, sq[8] = {0,0,0,0,0,0,0,0};
  for (int i = blockIdx.x * 256 + threadIdx.x; i < DHW_; i += gridDim.x * 256) {
    const uint4* p = (const uint4*)(x + ((size_t)b * DHW_ + i) * 16);
    uint4 q0 = p[0], q1 = p[1];
    unsigned us[8] = {q0.x, q0.y, q0.z, q0.w, q1.x, q1.y, q1.z, q1.w};
#pragma unroll
    for (int k = 0; k < 8; k++) {
      float v0 = bf_lo(us[k]), v1 = bf_hi(us[k]);
      sg[k] += v0 + v1;
      sq[k] += v0 * v0 + v1 * v1;
    }
  }
#pragma unroll
  for (int k = 0; k < 8; k++)
    for (int off = 32; off; off >>= 1) {
      sg[k] += __shfl_xor(sg[k], off, 64);
      sq[k] += __shfl_xor(sq[k], off, 64);
    }
  __shared__ float ls[4][16];
  int wid = threadIdx.x >> 6, lane = threadIdx.x & 63;
  if (lane == 0) {
#pragma unroll
    for (int k = 0; k < 8; k++) { ls[wid][k] = sg[k]; ls[wid][8 + k] = sq[k]; }
  }
  __syncthreads();
  if (threadIdx.x < 16) {
    float t = ls[0][threadIdx.x] + ls[1][threadIdx.x] + ls[2][threadIdx.x] + ls[3][threadIdx.x];
    int g = threadIdx.x & 7, which = threadIdx.x >> 3;
    atomicAdd(&st[(size_t)(b * 8 + g) * 2 + which], (double)t);
  }
}

// ---------------------------------------------------------------------------
// GN normalize + SiLU in place, channels-last bf16
// ---------------------------------------------------------------------------
__global__ __launch_bounds__(256)
void norm_cl_kernel(__bf16* __restrict__ x, const double* __restrict__ st,
                    const float* __restrict__ gamma, const float* __restrict__ beta,
                    double invN) {
  int b = blockIdx.y;
  __shared__ float scs[16], shs[16];
  if (threadIdx.x < 16) {
    int c = threadIdx.x, grp = c >> 1;
    double mean = st[(size_t)(b * 8 + grp) * 2] * invN;
    double var = st[(size_t)(b * 8 + grp) * 2 + 1] * invN - mean * mean;
    float sc = gamma[c] * rsqrtf((float)var + EPS_);
    scs[c] = sc;
    shs[c] = beta[c] - (float)mean * sc;
  }
  __syncthreads();
  float sc[16], sh[16];
#pragma unroll
  for (int c = 0; c < 16; c++) { sc[c] = scs[c]; sh[c] = shs[c]; }
  for (int i = blockIdx.x * 256 + threadIdx.x; i < DHW_; i += gridDim.x * 256) {
    uint4* p = (uint4*)(x + ((size_t)b * DHW_ + i) * 16);
    uint4 q0 = p[0], q1 = p[1];
    unsigned us[8] = {q0.x, q0.y, q0.z, q0.w, q1.x, q1.y, q1.z, q1.w};
    unsigned ro[8];
#pragma unroll
    for (int k = 0; k < 8; k++) {
      int c0 = 2 * k;
      float v0 = silu(bf_lo(us[k]) * sc[c0] + sh[c0]);
      float v1 = silu(bf_hi(us[k]) * sc[c0 + 1] + sh[c0 + 1]);
      ro[k] = pack2(v0, v1);
    }
    p[0] = make_uint4(ro[0], ro[1], ro[2], ro[3]);
    p[1] = make_uint4(ro[4], ro[5], ro[6], ro[7]);
  }
}

// ---------------------------------------------------------------------------
// conv3d #3 (16->1) + bias, LDS-tiled. Output tile: 3 d x 4 h x 64 w.
// LDS input tile [dd=5][hh=6][half=2][pos=66] of 16B vectors (8ch bf16) = 61.9KB
// + 432 weight floats. Grid: b(2) x dt(8) x ht(40) x wt(5) = 3200 blocks.
// ---------------------------------------------------------------------------
__global__ __launch_bounds__(256)
void conv3_tile_kernel(const __bf16* __restrict__ a2, const float* __restrict__ wt,
                       const float* __restrict__ bias, float* __restrict__ logits) {
  __shared__ __align__(16) __bf16 li[5 * 6 * 2 * 66 * 8];   // 63360 B
  __shared__ float lw[432];                                  // [tap][ci]
  int bid = blockIdx.x;
  int wtile = bid % 5; bid /= 5;
  int ht = bid % 40; bid /= 40;
  int dt = bid % 8; bid /= 8;
  int b = bid;
  const int d0 = dt * 3, h0 = ht * 4, w0 = wtile * 64;
  // stage weights (OIDHW, single output ch): lw[tap*16+ci] = wt[ci*27+tap]
  for (int i = threadIdx.x; i < 432; i += 256) {
    int tap = i >> 4, ci = i & 15;
    lw[i] = wt[ci * 27 + tap];
  }
  // stage inputs: 5*6*66 = 1980 positions, 32B (both halves) per position
  for (int idx = threadIdx.x; idx < 5 * 6 * 66; idx += 256) {
    int pos = idx % 66;
    int r = idx / 66;
    int hh = r % 6, dd = r / 6;
    int d = d0 + dd - 1, h = h0 + hh - 1, w = w0 + pos - 1;
    uint4 v0 = make_uint4(0, 0, 0, 0), v1 = v0;
    if ((unsigned)d < (unsigned)D_ && (unsigned)h < (unsigned)H_ && (unsigned)w < (unsigned)W_) {
      const uint4* p = (const uint4*)(a2 + ((size_t)(((b * D_ + d) * H_ + h) * W_ + w)) * 16);
      v0 = p[0];
      v1 = p[1];
    }
    int vb = ((dd * 6 + hh) * 2) * 66 + pos;       // half-0 vector index
    *(uint4*)(li + (size_t)vb * 8) = v0;
    *(uint4*)(li + (size_t)(vb + 66) * 8) = v1;    // half-1 plane
  }
  __syncthreads();
  const int ow = threadIdx.x & 63;
  const int oh = threadIdx.x >> 6;                 // 0..3 (uniform per wave)
  float acc[3] = {0.f, 0.f, 0.f};
  for (int kd = 0; kd < 3; kd++)
    for (int kh = 0; kh < 3; kh++)
      for (int kw = 0; kw < 3; kw++) {
        const int tap = kd * 9 + kh * 3 + kw;
        const float* wp = lw + tap * 16;
        float wv[16];
#pragma unroll
        for (int c = 0; c < 16; c++) wv[c] = wp[c];
        const int hh = oh + kh;
        const int pos = ow + kw;
#pragma unroll
        for (int od = 0; od < 3; od++) {
          const int dd = od + kd;
          const int vb = ((dd * 6 + hh) * 2) * 66 + pos;
          uint4 q0 = *(const uint4*)(li + (size_t)vb * 8);
          uint4 q1 = *(const uint4*)(li + (size_t)(vb + 66) * 8);
          acc[od] +=
            bf_lo(q0.x) * wv[0]  + bf_hi(q0.x) * wv[1]  + bf_lo(q0.y) * wv[2]  + bf_hi(q0.y) * wv[3] +
            bf_lo(q0.z) * wv[4]  + bf_hi(q0.z) * wv[5]  + bf_lo(q0.w) * wv[6]  + bf_hi(q0.w) * wv[7] +
            bf_lo(q1.x) * wv[8]  + bf_hi(q1.x) * wv[9]  + bf_lo(q1.y) * wv[10] + bf_hi(q1.y) * wv[11] +
            bf_lo(q1.z) * wv[12] + bf_hi(q1.z) * wv[13] + bf_lo(q1.w) * wv[14] + bf_hi(q1.w) * wv[15];
        }
      }
  const float bv = bias[0];
#pragma unroll
  for (int od = 0; od < 3; od++)
    logits[((size_t)(b * D_ + d0 + od) * H_ + (h0 + oh)) * W_ + w0 + ow] = acc[od] + bv;
}

// ---------------------------------------------------------------------------
// 3x3 conv2d, pad 1 (heads; fp32 channels-first) — unchanged
// ---------------------------------------------------------------------------
template <int C0, int C1, int COUT, bool HASBIAS, bool ADD_DSA>
__global__ __launch_bounds__(320)
void conv2d_kernel(const float* __restrict__ in0, const float* __restrict__ in1,
                   const float* __restrict__ wt, const float* __restrict__ bias,
                   const float* __restrict__ dsa, float* __restrict__ out) {
  constexpr int CINT = C0 + C1;
  __shared__ float lw[COUT * CINT * 9];
  for (int i = threadIdx.x; i < COUT * CINT * 9; i += 320) lw[i] = wt[i];
  __syncthreads();
  int w = threadIdx.x;
  int h = blockIdx.x % H_;
  int b = blockIdx.x / H_;
  float acc[COUT];
#pragma unroll
  for (int co = 0; co < COUT; co++) acc[co] = 0.f;
  for (int kh = 0; kh < 3; kh++) {
    int hh = h + kh - 1;
    if (hh < 0 || hh >= H_) continue;
    for (int kw = 0; kw < 3; kw++) {
      int ww = w + kw - 1;
      if (ww < 0 || ww >= W_) continue;
#pragma unroll
      for (int ci = 0; ci < C0; ci++) {
        float v = in0[((size_t)(b * C0 + ci)) * HW_ + hh * W_ + ww];
        const float* lwp = lw + (ci * 3 + kh) * 3 + kw;
#pragma unroll
        for (int co = 0; co < COUT; co++) acc[co] += v * lwp[co * CINT * 9];
      }
      if (C1 > 0) {
#pragma unroll
        for (int ci = 0; ci < (C1 > 0 ? C1 : 1); ci++) {
          float v = in1[((size_t)(b * C1 + ci)) * HW_ + hh * W_ + ww];
          const float* lwp = lw + ((C0 + ci) * 3 + kh) * 3 + kw;
#pragma unroll
          for (int co = 0; co < COUT; co++) acc[co] += v * lwp[co * CINT * 9];
        }
      }
    }
  }
#pragma unroll
  for (int co = 0; co < COUT; co++) {
    float r = acc[co];
    if (HASBIAS) r += bias[co];
    if (ADD_DSA) r += dsa[(size_t)b * HW_ + h * W_ + w];
    out[((size_t)(b * COUT + co)) * HW_ + h * W_ + w] = r;
  }
}

// ---------------------------------------------------------------------------
// Conv1d over flattened H*W axis — unchanged
// ---------------------------------------------------------------------------
__global__ __launch_bounds__(256)
void conv1d_kernel(const float* __restrict__ logits, const float* __restrict__ wt,
                   float* __restrict__ out) {
  __shared__ float lw[D_ * D_ * 3];
  for (int i = threadIdx.x; i < D_ * D_ * 3; i += 256) lw[i] = wt[i];
  __syncthreads();
  int idx = blockIdx.x * 256 + threadIdx.x;
  int b = idx / HW_;
  int i = idx % HW_;
  float acc[D_];
#pragma unroll
  for (int o = 0; o < D_; o++) acc[o] = 0.f;
  for (int k = 0; k < 3; k++) {
    int pos = i + k - 1;
    if (pos < 0 || pos >= HW_) continue;
#pragma unroll
    for (int din = 0; din < D_; din++) {
      float v = logits[((size_t)b * D_ + din) * HW_ + pos];
      const float* lwp = lw + din * 3 + k;
#pragma unroll
      for (int o = 0; o < D_; o++) acc[o] += v * lwp[o * D_ * 3];
    }
  }
#pragma unroll
  for (int o = 0; o < D_; o++) out[((size_t)b * D_ + o) * HW_ + i] = acc[o];
}

// ---------------------------------------------------------------------------
// GN stats fp32 channels-first (heads) — unchanged
// ---------------------------------------------------------------------------
__global__ __launch_bounds__(256)
void stats_kernel(const float* __restrict__ x, double* __restrict__ stats,
                  int Cc, int chg, size_t per_ch, int nchunk) {
  int tmp = blockIdx.x;
  int chunk = tmp % nchunk; tmp /= nchunk;
  int cig = tmp % chg; tmp /= chg;
  int grp = tmp % 8;
  int b = tmp / 8;
  int c = grp * chg + cig;
  size_t len = per_ch / nchunk;
  const float* p = x + ((size_t)b * Cc + c) * per_ch + (size_t)chunk * len;
  float s = 0.f, s2 = 0.f;
  for (size_t i = threadIdx.x; i < len; i += 256) {
    float v = p[i];
    s += v;
    s2 += v * v;
  }
  __shared__ double ls[256], ls2[256];
  ls[threadIdx.x] = (double)s;
  ls2[threadIdx.x] = (double)s2;
  __syncthreads();
  for (int off = 128; off > 0; off >>= 1) {
    if (threadIdx.x < off) {
      ls[threadIdx.x] += ls[threadIdx.x + off];
      ls2[threadIdx.x] += ls2[threadIdx.x + off];
    }
    __syncthreads();
  }
  if (threadIdx.x == 0) {
    atomicAdd(&stats[(size_t)(b * 8 + grp) * 2], ls[0]);
    atomicAdd(&stats[(size_t)(b * 8 + grp) * 2 + 1], ls2[0]);
  }
}

// norm+SiLU fp32 channels-first (heads) — unchanged
__global__ __launch_bounds__(256)
void norm_silu_f32o_kernel(const float* __restrict__ x, float* __restrict__ y,
                           const double* __restrict__ stats,
                           const float* __restrict__ gamma, const float* __restrict__ beta,
                           int chg, size_t per_ch, double invN) {
  int c = blockIdx.y;
  int b = blockIdx.z;
  int grp = c / chg;
  double s = stats[(size_t)(b * 8 + grp) * 2];
  double s2 = stats[(size_t)(b * 8 + grp) * 2 + 1];
  double mean_d = s * invN;
  double var_d = s2 * invN - mean_d * mean_d;
  float sc = gamma[c] / sqrtf((float)var_d + EPS_);
  float sh = beta[c] - (float)mean_d * sc;
  size_t base = ((size_t)b * gridDim.y + c) * per_ch;
  size_t chunk = (per_ch + gridDim.x - 1) / gridDim.x;
  size_t start = (size_t)blockIdx.x * chunk;
  size_t end = start + chunk;
  if (end > per_ch) end = per_ch;
  for (size_t i = start + threadIdx.x; i < end; i += 256) {
    float v = x[base + i] * sc + sh;
    y[base + i] = v / (1.f + __expf(-v));
  }
}

// ---------------------------------------------------------------------------
// Softmax over D + soft-argmin + confidence — unchanged
// ---------------------------------------------------------------------------
__global__ __launch_bounds__(320)
void softmax_kernel(const float* __restrict__ logits, float* __restrict__ dsa,
                    float* __restrict__ conf) {
  int w = threadIdx.x;
  int h = blockIdx.x % H_;
  int b = blockIdx.x / H_;
  size_t base = ((size_t)b * D_) * HW_ + h * W_ + w;
  float v[D_];
  float m = -1e30f;
#pragma unroll
  for (int d = 0; d < D_; d++) {
    v[d] = logits[base + (size_t)d * HW_];
    m = fmaxf(m, v[d]);
  }
  float s = 0.f, wd = 0.f;
#pragma unroll
  for (int d = 0; d < D_; d++) {
    float e = __expf(v[d] - m);
    s += e;
    wd += (float)d * e;
  }
  float inv = 1.f / s;
  dsa[(size_t)b * HW_ + h * W_ + w] = wd * inv;
  conf[(size_t)b * HW_ + h * W_ + w] = inv;  // max prob
}

// ---------------------------------------------------------------------------

extern "C" void kernel_launch(void* const* d_in, const int* in_sizes, int n_in,
                              void* d_out, int out_size, void* d_ws, size_t ws_size,
                              hipStream_t stream) {
  const float* fL = (const float*)d_in[0];
  const float* fR = (const float*)d_in[1];
  const float* agg_w1 = (const float*)d_in[2];
  const float* agg_g1 = (const float*)d_in[3];
  const float* agg_b1 = (const float*)d_in[4];
  const float* agg_w2 = (const float*)d_in[5];
  const float* agg_g2 = (const float*)d_in[6];
  const float* agg_b2 = (const float*)d_in[7];
  const float* agg_w3 = (const float*)d_in[8];
  const float* agg_bias3 = (const float*)d_in[9];
  const float* feat_w = (const float*)d_in[10];
  const float* feat_g = (const float*)d_in[11];
  const float* feat_b = (const float*)d_in[12];
  const float* apc_w = (const float*)d_in[13];
  const float* reg_w1 = (const float*)d_in[14];
  const float* reg_g1 = (const float*)d_in[15];
  const float* reg_b1 = (const float*)d_in[16];
  const float* reg_w2 = (const float*)d_in[17];
  const float* reg_bias2 = (const float*)d_in[18];

  char* wsb = (char*)d_ws;
  // Region A [0, 78.6MB): a1 (bf16 CL); after conv2 consumed it, reused for
  // small fp32 buffers. Region B [78.6MB, 157.3MB): cv then a2 (cv dead).
  constexpr size_t REG = 78643200ull;
  __bf16* a1 = (__bf16*)wsb;
  __bf16* cvb = (__bf16*)(wsb + REG);
  __bf16* a2 = (__bf16*)(wsb + REG);
  float* logits = (float*)wsb;                   // 2,457,600 f
  float* apc = logits + 2457600;                 // 2,457,600 f
  float* h2 = apc + 2457600;                     // 3,276,800 f
  float* dsa = h2 + 3276800;                     //   102,400 f
  float* featraw = dsa + 102400;                 // 1,638,400 f
  __bf16* wf1 = (__bf16*)(wsb + 2 * REG);        // 3584 elems
  __bf16* wf2 = wf1 + 3584;                      // 7168 elems
  double* stats = (double*)(wsb + 2 * REG + 21504);  // 128 doubles

  float* out = (float*)d_out;
  float* out_dinit = out;                        // [B,1,H,W]
  float* out_sx = out + 102400;                  // zeros (sx, sy)
  float* out_feat = out + 307200;                // [B,16,H,W]
  float* out_conf = out + 1945600;               // [B,1,H,W]

  hipMemsetAsync(stats, 0, 128 * sizeof(double), stream);
  hipMemsetAsync(out_sx, 0, 2 * 102400 * sizeof(float), stream);

  // weight fragments
  wprep_kernel<<<1, 64, 0, stream>>>(agg_w1, agg_w2, wf1, wf2);

  // cost volume (channels-last bf16)
  cv_cl_kernel<<<dim3(B_ * H_, 4), 320, 0, stream>>>(fL, fR, cvb);

  // agg conv1 (8->16) MFMA ; GN ; SiLU
  conv3d_mfma_kernel<8, 7><<<B_ * D_ * H_, 256, 0, stream>>>(cvb, wf1, a1);
  stats_cl_kernel<<<dim3(256, B_), 256, 0, stream>>>(a1, stats + 0);
  norm_cl_kernel<<<dim3(512, B_), 256, 0, stream>>>(a1, stats + 0, agg_g1, agg_b1,
                                                    1.0 / (2.0 * DHW_));

  // agg conv2 (16->16) MFMA ; GN ; SiLU
  conv3d_mfma_kernel<16, 14><<<B_ * D_ * H_, 256, 0, stream>>>(a1, wf2, a2);
  stats_cl_kernel<<<dim3(256, B_), 256, 0, stream>>>(a2, stats + 32);
  norm_cl_kernel<<<dim3(512, B_), 256, 0, stream>>>(a2, stats + 32, agg_g2, agg_b2,
                                                    1.0 / (2.0 * DHW_));

  // agg conv3 (16->1) + bias -> logits (fp32, [B,D,H,W]), LDS-tiled
  conv3_tile_kernel<<<3200, 256, 0, stream>>>(a2, agg_w3, agg_bias3, logits);

  // softmax -> dsa (ws), conf (out)
  softmax_kernel<<<B_ * H_, 320, 0, stream>>>(logits, dsa, out_conf);

  // feat head: conv2d(64->16) ; GN ; SiLU -> out_feat
  conv2d_kernel<C_, 0, 16, false, false><<<B_ * H_, 320, 0, stream>>>(
      fL, nullptr, feat_w, nullptr, nullptr, featraw);
  stats_kernel<<<B_ * 8 * 2 * 8, 256, 0, stream>>>(featraw, stats + 64, 16, 2, (size_t)HW_, 8);
  norm_silu_f32o_kernel<<<dim3(50, 16, B_), 256, 0, stream>>>(featraw, out_feat, stats + 64,
                                                              feat_g, feat_b, 2, (size_t)HW_,
                                                              1.0 / (2.0 * HW_));

  // apc conv1d on flattened logits
  conv1d_kernel<<<(B_ * HW_) / 256, 256, 0, stream>>>(logits, apc_w, apc);

  // regression head conv1 (24+16 -> 32) ; GN ; SiLU
  conv2d_kernel<D_, 16, 32, false, false><<<B_ * H_, 320, 0, stream>>>(
      apc, out_feat, reg_w1, nullptr, nullptr, h2);
  stats_kernel<<<B_ * 8 * 4 * 8, 256, 0, stream>>>(h2, stats + 96, 32, 4, (size_t)HW_, 8);
  norm_silu_f32o_kernel<<<dim3(50, 32, B_), 256, 0, stream>>>(h2, h2, stats + 96, reg_g1, reg_b1,
                                                              4, (size_t)HW_, 1.0 / (4.0 * HW_));

  // regression conv2 (32->1) + bias + d_sa -> d_init
  conv2d_kernel<32, 0, 1, true, true><<<B_ * H_, 320, 0, stream>>>(
      h2, nullptr, reg_w2, reg_bias2, dsa, out_dinit);
}

// Round 10
// 858.499 us; speedup vs baseline: 3.0151x; 1.2663x over previous
//
#include <hip/hip_runtime.h>
#include <hip/hip_bf16.h>
#include <math.h>

// Problem constants
constexpr int B_ = 2;
constexpr int C_ = 64;
constexpr int H_ = 160;
constexpr int W_ = 320;
constexpr int G_ = 8;       // correlation groups
constexpr int D_ = 24;      // max disparity
constexpr int HW_ = H_ * W_;        // 51200
constexpr int DHW_ = D_ * HW_;      // 1228800
constexpr float EPS_ = 1e-5f;

typedef __bf16 b8 __attribute__((ext_vector_type(8)));
typedef float  f4 __attribute__((ext_vector_type(4)));

__device__ inline float bf_lo(unsigned u) { return __builtin_bit_cast(float, u << 16); }
__device__ inline float bf_hi(unsigned u) { return __builtin_bit_cast(float, u & 0xffff0000u); }
__device__ inline unsigned pack2(float a, float b) {
  unsigned lo = __builtin_bit_cast(unsigned short, (__bf16)a);
  unsigned hi = __builtin_bit_cast(unsigned short, (__bf16)b);
  return (hi << 16) | lo;
}
__device__ inline float silu(float v) { return v / (1.f + __expf(-v)); }

// ---------------------------------------------------------------------------
// Cost volume, channels-last bf16: cv[b,d,h,w,g] = mean_c fL[g*8+c]*fR[g*8+c] shifted
// ---------------------------------------------------------------------------
__global__ __launch_bounds__(320)
void cv_cl_kernel(const float* __restrict__ fL, const float* __restrict__ fR,
                  __bf16* __restrict__ cv) {
  int w = threadIdx.x;
  int h = blockIdx.x % H_;
  int b = blockIdx.x / H_;
  int d0 = blockIdx.y * 6;
  const size_t rowbase = ((size_t)(b * C_) * H_ + h) * W_;
  float l[C_];
#pragma unroll
  for (int c = 0; c < C_; c++) l[c] = fL[rowbase + (size_t)c * HW_ + w];
  for (int dd = 0; dd < 6; dd++) {
    int d = d0 + dd;
    float s[8] = {0.f,0.f,0.f,0.f,0.f,0.f,0.f,0.f};
    if (w >= d) {
      const float* pr = fR + rowbase + (w - d);
#pragma unroll
      for (int c = 0; c < C_; c++) s[c >> 3] += l[c] * pr[(size_t)c * HW_];
    }
    b8 r;
#pragma unroll
    for (int g = 0; g < 8; g++) r[g] = (__bf16)(s[g] * 0.125f);
    *(b8*)(cv + ((size_t)((b * D_ + d) * H_ + h) * W_ + w) * 8) = r;
  }
}

// ---------------------------------------------------------------------------
// Weight prep: per-lane MFMA B-fragments. K order = taps x ci (ci fastest).
// ---------------------------------------------------------------------------
__global__ void wprep_kernel(const float* __restrict__ w1, const float* __restrict__ w2,
                             __bf16* __restrict__ wf1, __bf16* __restrict__ wf2) {
  int lane = threadIdx.x;      // 64 threads
  int co = lane & 15, kb = lane >> 4;
#pragma unroll
  for (int p = 0; p < 7; p++)
#pragma unroll
    for (int j = 0; j < 8; j++) {
      int kl = kb * 8 + j;
      int tap = p * 4 + (kl >> 3);
      int ci = kl & 7;
      float v = (tap <= 26) ? w1[(co * 8 + ci) * 27 + tap] : 0.f;
      wf1[(p * 64 + lane) * 8 + j] = (__bf16)v;
    }
#pragma unroll
  for (int p = 0; p < 14; p++)
#pragma unroll
    for (int j = 0; j < 8; j++) {
      int kl = kb * 8 + j;
      int tap = p * 2 + (kl >> 4);
      int ci = kl & 15;
      float v = (tap <= 26) ? w2[(co * 16 + ci) * 27 + tap] : 0.f;
      wf2[(p * 64 + lane) * 8 + j] = (__bf16)v;
    }
}

// ---------------------------------------------------------------------------
// 3x3x3 conv3d as implicit-GEMM MFMA. Channels-last bf16 in/out (out: 16 ch).
// ---------------------------------------------------------------------------
template <int CIN, int PAIRS>
__global__ __launch_bounds__(256)
void conv3d_mfma_kernel(const __bf16* __restrict__ in, const __bf16* __restrict__ wf,
                        __bf16* __restrict__ out) {
  const int lane = threadIdx.x & 63;
  const int wid = threadIdx.x >> 6;
  const int bid = blockIdx.x;              // (b*24+d)*160 + h
  const int h = bid % H_;
  const int d = (bid / H_) % D_;
  const int m = lane & 15;
  const int tpp = 32 / CIN;                // taps per K-tile
  const int tapsel = (CIN == 16) ? (lane >> 5) : (lane >> 4);
  const int ci0 = (CIN == 16) ? ((lane >> 1) & 8) : 0;
  b8 wfr[PAIRS];
#pragma unroll
  for (int p = 0; p < PAIRS; p++) wfr[p] = *(const b8*)(wf + (p * 64 + lane) * 8);
  int poff[PAIRS], dwv[PAIRS];
  bool vdh[PAIRS];
#pragma unroll
  for (int p = 0; p < PAIRS; p++) {
    int tap = p * tpp + tapsel;
    if (tap > 26) tap = 26;                // dummy half has zero weights
    int kd = tap / 9, kh = (tap / 3) % 3, kw = tap % 3;
    poff[p] = (kd - 1) * HW_ + (kh - 1) * W_ + (kw - 1);
    dwv[p] = kw - 1;
    vdh[p] = ((unsigned)(d + kd - 1) < (unsigned)D_) &&
             ((unsigned)(h + kh - 1) < (unsigned)H_);
  }
  const int pos0row = bid * W_;
  for (int t = 0; t < 5; t++) {
    const int w0 = (wid * 5 + t) * 16;
    const int pos0 = pos0row + w0;
    f4 acc = {0.f, 0.f, 0.f, 0.f};
#pragma unroll
    for (int p = 0; p < PAIRS; p++) {
      b8 a = {};
      if (vdh[p] && ((unsigned)(w0 + m + dwv[p]) < (unsigned)W_))
        a = *(const b8*)(in + (long)(pos0 + m + poff[p]) * CIN + ci0);
      acc = __builtin_amdgcn_mfma_f32_16x16x32_bf16(a, wfr[p], acc, 0, 0, 0);
    }
    const int co = lane & 15;
    const int r0 = (lane >> 4) * 4;
#pragma unroll
    for (int r = 0; r < 4; r++)
      out[(size_t)(pos0 + r0 + r) * 16 + co] = (__bf16)acc[r];
  }
}

// ---------------------------------------------------------------------------
// GN stats, channels-last bf16 [b][pos][16]
// ---------------------------------------------------------------------------
__global__ __launch_bounds__(256)
void stats_cl_kernel(const __bf16* __restrict__ x, double* __restrict__ st) {
  int b = blockIdx.y;
  float sg[8] = {0,0,0,0,0,0,0,0}, sq[8] = {0,0,0,0,0,0,0,0};
  for (int i = blockIdx.x * 256 + threadIdx.x; i < DHW_; i += gridDim.x * 256) {
    const uint4* p = (const uint4*)(x + ((size_t)b * DHW_ + i) * 16);
    uint4 q0 = p[0], q1 = p[1];
    unsigned us[8] = {q0.x, q0.y, q0.z, q0.w, q1.x, q1.y, q1.z, q1.w};
#pragma unroll
    for (int k = 0; k < 8; k++) {
      float v0 = bf_lo(us[k]), v1 = bf_hi(us[k]);
      sg[k] += v0 + v1;
      sq[k] += v0 * v0 + v1 * v1;
    }
  }
#pragma unroll
  for (int k = 0; k < 8; k++)
    for (int off = 32; off; off >>= 1) {
      sg[k] += __shfl_xor(sg[k], off, 64);
      sq[k] += __shfl_xor(sq[k], off, 64);
    }
  __shared__ float ls[4][16];
  int wid = threadIdx.x >> 6, lane = threadIdx.x & 63;
  if (lane == 0) {
#pragma unroll
    for (int k = 0; k < 8; k++) { ls[wid][k] = sg[k]; ls[wid][8 + k] = sq[k]; }
  }
  __syncthreads();
  if (threadIdx.x < 16) {
    float t = ls[0][threadIdx.x] + ls[1][threadIdx.x] + ls[2][threadIdx.x] + ls[3][threadIdx.x];
    int g = threadIdx.x & 7, which = threadIdx.x >> 3;
    atomicAdd(&st[(size_t)(b * 8 + g) * 2 + which], (double)t);
  }
}

// ---------------------------------------------------------------------------
// GN normalize + SiLU in place, channels-last bf16
// ---------------------------------------------------------------------------
__global__ __launch_bounds__(256)
void norm_cl_kernel(__bf16* __restrict__ x, const double* __restrict__ st,
                    const float* __restrict__ gamma, const float* __restrict__ beta,
                    double invN) {
  int b = blockIdx.y;
  __shared__ float scs[16], shs[16];
  if (threadIdx.x < 16) {
    int c = threadIdx.x, grp = c >> 1;
    double mean = st[(size_t)(b * 8 + grp) * 2] * invN;
    double var = st[(size_t)(b * 8 + grp) * 2 + 1] * invN - mean * mean;
    float sc = gamma[c] * rsqrtf((float)var + EPS_);
    scs[c] = sc;
    shs[c] = beta[c] - (float)mean * sc;
  }
  __syncthreads();
  float sc[16], sh[16];
#pragma unroll
  for (int c = 0; c < 16; c++) { sc[c] = scs[c]; sh[c] = shs[c]; }
  for (int i = blockIdx.x * 256 + threadIdx.x; i < DHW_; i += gridDim.x * 256) {
    uint4* p = (uint4*)(x + ((size_t)b * DHW_ + i) * 16);
    uint4 q0 = p[0], q1 = p[1];
    unsigned us[8] = {q0.x, q0.y, q0.z, q0.w, q1.x, q1.y, q1.z, q1.w};
    unsigned ro[8];
#pragma unroll
    for (int k = 0; k < 8; k++) {
      int c0 = 2 * k;
      float v0 = silu(bf_lo(us[k]) * sc[c0] + sh[c0]);
      float v1 = silu(bf_hi(us[k]) * sc[c0 + 1] + sh[c0 + 1]);
      ro[k] = pack2(v0, v1);
    }
    p[0] = make_uint4(ro[0], ro[1], ro[2], ro[3]);
    p[1] = make_uint4(ro[4], ro[5], ro[6], ro[7]);
  }
}

// ---------------------------------------------------------------------------
// conv3d #3 (16->1) + bias, LDS-tiled. Output tile: 3 d x 4 h x 64 w.
// ---------------------------------------------------------------------------
__global__ __launch_bounds__(256)
void conv3_tile_kernel(const __bf16* __restrict__ a2, const float* __restrict__ wt,
                       const float* __restrict__ bias, float* __restrict__ logits) {
  __shared__ __align__(16) __bf16 li[5 * 6 * 2 * 66 * 8];   // 63360 B
  __shared__ float lw[432];                                  // [tap][ci]
  int bid = blockIdx.x;
  int wtile = bid % 5; bid /= 5;
  int ht = bid % 40; bid /= 40;
  int dt = bid % 8; bid /= 8;
  int b = bid;
  const int d0 = dt * 3, h0 = ht * 4, w0 = wtile * 64;
  for (int i = threadIdx.x; i < 432; i += 256) {
    int tap = i >> 4, ci = i & 15;
    lw[i] = wt[ci * 27 + tap];
  }
  for (int idx = threadIdx.x; idx < 5 * 6 * 66; idx += 256) {
    int pos = idx % 66;
    int r = idx / 66;
    int hh = r % 6, dd = r / 6;
    int d = d0 + dd - 1, h = h0 + hh - 1, w = w0 + pos - 1;
    uint4 v0 = make_uint4(0, 0, 0, 0), v1 = v0;
    if ((unsigned)d < (unsigned)D_ && (unsigned)h < (unsigned)H_ && (unsigned)w < (unsigned)W_) {
      const uint4* p = (const uint4*)(a2 + ((size_t)(((b * D_ + d) * H_ + h) * W_ + w)) * 16);
      v0 = p[0];
      v1 = p[1];
    }
    int vb = ((dd * 6 + hh) * 2) * 66 + pos;       // half-0 vector index
    *(uint4*)(li + (size_t)vb * 8) = v0;
    *(uint4*)(li + (size_t)(vb + 66) * 8) = v1;    // half-1 plane
  }
  __syncthreads();
  const int ow = threadIdx.x & 63;
  const int oh = threadIdx.x >> 6;                 // 0..3 (uniform per wave)
  float acc[3] = {0.f, 0.f, 0.f};
  for (int kd = 0; kd < 3; kd++)
    for (int kh = 0; kh < 3; kh++)
      for (int kw = 0; kw < 3; kw++) {
        const int tap = kd * 9 + kh * 3 + kw;
        const float* wp = lw + tap * 16;
        float wv[16];
#pragma unroll
        for (int c = 0; c < 16; c++) wv[c] = wp[c];
        const int hh = oh + kh;
        const int pos = ow + kw;
#pragma unroll
        for (int od = 0; od < 3; od++) {
          const int dd = od + kd;
          const int vb = ((dd * 6 + hh) * 2) * 66 + pos;
          uint4 q0 = *(const uint4*)(li + (size_t)vb * 8);
          uint4 q1 = *(const uint4*)(li + (size_t)(vb + 66) * 8);
          acc[od] +=
            bf_lo(q0.x) * wv[0]  + bf_hi(q0.x) * wv[1]  + bf_lo(q0.y) * wv[2]  + bf_hi(q0.y) * wv[3] +
            bf_lo(q0.z) * wv[4]  + bf_hi(q0.z) * wv[5]  + bf_lo(q0.w) * wv[6]  + bf_hi(q0.w) * wv[7] +
            bf_lo(q1.x) * wv[8]  + bf_hi(q1.x) * wv[9]  + bf_lo(q1.y) * wv[10] + bf_hi(q1.y) * wv[11] +
            bf_lo(q1.z) * wv[12] + bf_hi(q1.z) * wv[13] + bf_lo(q1.w) * wv[14] + bf_hi(q1.w) * wv[15];
        }
      }
  const float bv = bias[0];
#pragma unroll
  for (int od = 0; od < 3; od++)
    logits[((size_t)(b * D_ + d0 + od) * H_ + (h0 + oh)) * W_ + w0 + ow] = acc[od] + bv;
}

// ---------------------------------------------------------------------------
// 3x3 conv2d, pad 1 (heads; fp32 channels-first), output-channel-split:
// blockIdx.y picks a tile of COUT/COT channels. Weights for only that tile
// staged in LDS -> small LDS, more blocks, higher occupancy.
// ---------------------------------------------------------------------------
template <int C0, int C1, int COUT, int COT, bool HASBIAS, bool ADD_DSA>
__global__ __launch_bounds__(320)
void conv2d_kernel(const float* __restrict__ in0, const float* __restrict__ in1,
                   const float* __restrict__ wt, const float* __restrict__ bias,
                   const float* __restrict__ dsa, float* __restrict__ out) {
  constexpr int CINT = C0 + C1;
  constexpr int CL = COUT / COT;           // channels per block
  __shared__ float lw[CL * CINT * 9];
  const int co0 = blockIdx.y * CL;
  for (int i = threadIdx.x; i < CL * CINT * 9; i += 320) lw[i] = wt[co0 * CINT * 9 + i];
  __syncthreads();
  int w = threadIdx.x;
  int h = blockIdx.x % H_;
  int b = blockIdx.x / H_;
  float acc[CL];
#pragma unroll
  for (int co = 0; co < CL; co++) acc[co] = 0.f;
  for (int kh = 0; kh < 3; kh++) {
    int hh = h + kh - 1;
    if (hh < 0 || hh >= H_) continue;
    for (int kw = 0; kw < 3; kw++) {
      int ww = w + kw - 1;
      if (ww < 0 || ww >= W_) continue;
#pragma unroll
      for (int ci = 0; ci < C0; ci++) {
        float v = in0[((size_t)(b * C0 + ci)) * HW_ + hh * W_ + ww];
        const float* lwp = lw + (ci * 3 + kh) * 3 + kw;
#pragma unroll
        for (int co = 0; co < CL; co++) acc[co] += v * lwp[co * CINT * 9];
      }
      if (C1 > 0) {
#pragma unroll
        for (int ci = 0; ci < (C1 > 0 ? C1 : 1); ci++) {
          float v = in1[((size_t)(b * C1 + ci)) * HW_ + hh * W_ + ww];
          const float* lwp = lw + ((C0 + ci) * 3 + kh) * 3 + kw;
#pragma unroll
          for (int co = 0; co < CL; co++) acc[co] += v * lwp[co * CINT * 9];
        }
      }
    }
  }
#pragma unroll
  for (int co = 0; co < CL; co++) {
    float r = acc[co];
    if (HASBIAS) r += bias[co0 + co];
    if (ADD_DSA) r += dsa[(size_t)b * HW_ + h * W_ + w];
    out[((size_t)(b * COUT + co0 + co)) * HW_ + h * W_ + w] = r;
  }
}

// ---------------------------------------------------------------------------
// Conv1d over flattened H*W axis — unchanged
// ---------------------------------------------------------------------------
__global__ __launch_bounds__(256)
void conv1d_kernel(const float* __restrict__ logits, const float* __restrict__ wt,
                   float* __restrict__ out) {
  __shared__ float lw[D_ * D_ * 3];
  for (int i = threadIdx.x; i < D_ * D_ * 3; i += 256) lw[i] = wt[i];
  __syncthreads();
  int idx = blockIdx.x * 256 + threadIdx.x;
  int b = idx / HW_;
  int i = idx % HW_;
  float acc[D_];
#pragma unroll
  for (int o = 0; o < D_; o++) acc[o] = 0.f;
  for (int k = 0; k < 3; k++) {
    int pos = i + k - 1;
    if (pos < 0 || pos >= HW_) continue;
#pragma unroll
    for (int din = 0; din < D_; din++) {
      float v = logits[((size_t)b * D_ + din) * HW_ + pos];
      const float* lwp = lw + din * 3 + k;
#pragma unroll
      for (int o = 0; o < D_; o++) acc[o] += v * lwp[o * D_ * 3];
    }
  }
#pragma unroll
  for (int o = 0; o < D_; o++) out[((size_t)b * D_ + o) * HW_ + i] = acc[o];
}

// ---------------------------------------------------------------------------
// GN stats fp32 channels-first (heads) — unchanged
// ---------------------------------------------------------------------------
__global__ __launch_bounds__(256)
void stats_kernel(const float* __restrict__ x, double* __restrict__ stats,
                  int Cc, int chg, size_t per_ch, int nchunk) {
  int tmp = blockIdx.x;
  int chunk = tmp % nchunk; tmp /= nchunk;
  int cig = tmp % chg; tmp /= chg;
  int grp = tmp % 8;
  int b = tmp / 8;
  int c = grp * chg + cig;
  size_t len = per_ch / nchunk;
  const float* p = x + ((size_t)b * Cc + c) * per_ch + (size_t)chunk * len;
  float s = 0.f, s2 = 0.f;
  for (size_t i = threadIdx.x; i < len; i += 256) {
    float v = p[i];
    s += v;
    s2 += v * v;
  }
  __shared__ double ls[256], ls2[256];
  ls[threadIdx.x] = (double)s;
  ls2[threadIdx.x] = (double)s2;
  __syncthreads();
  for (int off = 128; off > 0; off >>= 1) {
    if (threadIdx.x < off) {
      ls[threadIdx.x] += ls[threadIdx.x + off];
      ls2[threadIdx.x] += ls2[threadIdx.x + off];
    }
    __syncthreads();
  }
  if (threadIdx.x == 0) {
    atomicAdd(&stats[(size_t)(b * 8 + grp) * 2], ls[0]);
    atomicAdd(&stats[(size_t)(b * 8 + grp) * 2 + 1], ls2[0]);
  }
}

// norm+SiLU fp32 channels-first (heads) — unchanged
__global__ __launch_bounds__(256)
void norm_silu_f32o_kernel(const float* __restrict__ x, float* __restrict__ y,
                           const double* __restrict__ stats,
                           const float* __restrict__ gamma, const float* __restrict__ beta,
                           int chg, size_t per_ch, double invN) {
  int c = blockIdx.y;
  int b = blockIdx.z;
  int grp = c / chg;
  double s = stats[(size_t)(b * 8 + grp) * 2];
  double s2 = stats[(size_t)(b * 8 + grp) * 2 + 1];
  double mean_d = s * invN;
  double var_d = s2 * invN - mean_d * mean_d;
  float sc = gamma[c] / sqrtf((float)var_d + EPS_);
  float sh = beta[c] - (float)mean_d * sc;
  size_t base = ((size_t)b * gridDim.y + c) * per_ch;
  size_t chunk = (per_ch + gridDim.x - 1) / gridDim.x;
  size_t start = (size_t)blockIdx.x * chunk;
  size_t end = start + chunk;
  if (end > per_ch) end = per_ch;
  for (size_t i = start + threadIdx.x; i < end; i += 256) {
    float v = x[base + i] * sc + sh;
    y[base + i] = v / (1.f + __expf(-v));
  }
}

// ---------------------------------------------------------------------------
// Softmax over D + soft-argmin + confidence — unchanged
// ---------------------------------------------------------------------------
__global__ __launch_bounds__(320)
void softmax_kernel(const float* __restrict__ logits, float* __restrict__ dsa,
                    float* __restrict__ conf) {
  int w = threadIdx.x;
  int h = blockIdx.x % H_;
  int b = blockIdx.x / H_;
  size_t base = ((size_t)b * D_) * HW_ + h * W_ + w;
  float v[D_];
  float m = -1e30f;
#pragma unroll
  for (int d = 0; d < D_; d++) {
    v[d] = logits[base + (size_t)d * HW_];
    m = fmaxf(m, v[d]);
  }
  float s = 0.f, wd = 0.f;
#pragma unroll
  for (int d = 0; d < D_; d++) {
    float e = __expf(v[d] - m);
    s += e;
    wd += (float)d * e;
  }
  float inv = 1.f / s;
  dsa[(size_t)b * HW_ + h * W_ + w] = wd * inv;
  conf[(size_t)b * HW_ + h * W_ + w] = inv;  // max prob
}

// ---------------------------------------------------------------------------

extern "C" void kernel_launch(void* const* d_in, const int* in_sizes, int n_in,
                              void* d_out, int out_size, void* d_ws, size_t ws_size,
                              hipStream_t stream) {
  const float* fL = (const float*)d_in[0];
  const float* fR = (const float*)d_in[1];
  const float* agg_w1 = (const float*)d_in[2];
  const float* agg_g1 = (const float*)d_in[3];
  const float* agg_b1 = (const float*)d_in[4];
  const float* agg_w2 = (const float*)d_in[5];
  const float* agg_g2 = (const float*)d_in[6];
  const float* agg_b2 = (const float*)d_in[7];
  const float* agg_w3 = (const float*)d_in[8];
  const float* agg_bias3 = (const float*)d_in[9];
  const float* feat_w = (const float*)d_in[10];
  const float* feat_g = (const float*)d_in[11];
  const float* feat_b = (const float*)d_in[12];
  const float* apc_w = (const float*)d_in[13];
  const float* reg_w1 = (const float*)d_in[14];
  const float* reg_g1 = (const float*)d_in[15];
  const float* reg_b1 = (const float*)d_in[16];
  const float* reg_w2 = (const float*)d_in[17];
  const float* reg_bias2 = (const float*)d_in[18];

  char* wsb = (char*)d_ws;
  // Region A [0, 78.6MB): a1 (bf16 CL); after conv2 consumed it, reused for
  // small fp32 buffers. Region B [78.6MB, 157.3MB): cv then a2 (cv dead).
  constexpr size_t REG = 78643200ull;
  __bf16* a1 = (__bf16*)wsb;
  __bf16* cvb = (__bf16*)(wsb + REG);
  __bf16* a2 = (__bf16*)(wsb + REG);
  float* logits = (float*)wsb;                   // 2,457,600 f
  float* apc = logits + 2457600;                 // 2,457,600 f
  float* h2 = apc + 2457600;                     // 3,276,800 f
  float* dsa = h2 + 3276800;                     //   102,400 f
  float* featraw = dsa + 102400;                 // 1,638,400 f
  __bf16* wf1 = (__bf16*)(wsb + 2 * REG);        // 3584 elems
  __bf16* wf2 = wf1 + 3584;                      // 7168 elems
  double* stats = (double*)(wsb + 2 * REG + 21504);  // 128 doubles

  float* out = (float*)d_out;
  float* out_dinit = out;                        // [B,1,H,W]
  float* out_sx = out + 102400;                  // zeros (sx, sy)
  float* out_feat = out + 307200;                // [B,16,H,W]
  float* out_conf = out + 1945600;               // [B,1,H,W]

  hipMemsetAsync(stats, 0, 128 * sizeof(double), stream);
  hipMemsetAsync(out_sx, 0, 2 * 102400 * sizeof(float), stream);

  // weight fragments
  wprep_kernel<<<1, 64, 0, stream>>>(agg_w1, agg_w2, wf1, wf2);

  // cost volume (channels-last bf16)
  cv_cl_kernel<<<dim3(B_ * H_, 4), 320, 0, stream>>>(fL, fR, cvb);

  // agg conv1 (8->16) MFMA ; GN ; SiLU
  conv3d_mfma_kernel<8, 7><<<B_ * D_ * H_, 256, 0, stream>>>(cvb, wf1, a1);
  stats_cl_kernel<<<dim3(256, B_), 256, 0, stream>>>(a1, stats + 0);
  norm_cl_kernel<<<dim3(512, B_), 256, 0, stream>>>(a1, stats + 0, agg_g1, agg_b1,
                                                    1.0 / (2.0 * DHW_));

  // agg conv2 (16->16) MFMA ; GN ; SiLU
  conv3d_mfma_kernel<16, 14><<<B_ * D_ * H_, 256, 0, stream>>>(a1, wf2, a2);
  stats_cl_kernel<<<dim3(256, B_), 256, 0, stream>>>(a2, stats + 32);
  norm_cl_kernel<<<dim3(512, B_), 256, 0, stream>>>(a2, stats + 32, agg_g2, agg_b2,
                                                    1.0 / (2.0 * DHW_));

  // agg conv3 (16->1) + bias -> logits (fp32, [B,D,H,W]), LDS-tiled
  conv3_tile_kernel<<<3200, 256, 0, stream>>>(a2, agg_w3, agg_bias3, logits);

  // softmax -> dsa (ws), conf (out)
  softmax_kernel<<<B_ * H_, 320, 0, stream>>>(logits, dsa, out_conf);

  // feat head: conv2d(64->16, 2 co-tiles) ; GN ; SiLU -> out_feat
  conv2d_kernel<C_, 0, 16, 2, false, false><<<dim3(B_ * H_, 2), 320, 0, stream>>>(
      fL, nullptr, feat_w, nullptr, nullptr, featraw);
  stats_kernel<<<B_ * 8 * 2 * 8, 256, 0, stream>>>(featraw, stats + 64, 16, 2, (size_t)HW_, 8);
  norm_silu_f32o_kernel<<<dim3(50, 16, B_), 256, 0, stream>>>(featraw, out_feat, stats + 64,
                                                              feat_g, feat_b, 2, (size_t)HW_,
                                                              1.0 / (2.0 * HW_));

  // apc conv1d on flattened logits
  conv1d_kernel<<<(B_ * HW_) / 256, 256, 0, stream>>>(logits, apc_w, apc);

  // regression head conv1 (24+16 -> 32, 4 co-tiles) ; GN ; SiLU
  conv2d_kernel<D_, 16, 32, 4, false, false><<<dim3(B_ * H_, 4), 320, 0, stream>>>(
      apc, out_feat, reg_w1, nullptr, nullptr, h2);
  stats_kernel<<<B_ * 8 * 4 * 8, 256, 0, stream>>>(h2, stats + 96, 32, 4, (size_t)HW_, 8);
  norm_silu_f32o_kernel<<<dim3(50, 32, B_), 256, 0, stream>>>(h2, h2, stats + 96, reg_g1, reg_b1,
                                                              4, (size_t)HW_, 1.0 / (4.0 * HW_));

  // regression conv2 (32->1) + bias + d_sa -> d_init
  conv2d_kernel<32, 0, 1, 1, true, true><<<dim3(B_ * H_, 1), 320, 0, stream>>>(
      h2, nullptr, reg_w2, reg_bias2, dsa, out_dinit);
}

// Round 11
// 840.466 us; speedup vs baseline: 3.0797x; 1.0215x over previous
//
#include <hip/hip_runtime.h>
#include <hip/hip_bf16.h>
#include <math.h>

// Problem constants
constexpr int B_ = 2;
constexpr int C_ = 64;
constexpr int H_ = 160;
constexpr int W_ = 320;
constexpr int G_ = 8;       // correlation groups
constexpr int D_ = 24;      // max disparity
constexpr int HW_ = H_ * W_;        // 51200
constexpr int DHW_ = D_ * HW_;      // 1228800
constexpr float EPS_ = 1e-5f;

typedef __bf16 b8 __attribute__((ext_vector_type(8)));
typedef float  f4 __attribute__((ext_vector_type(4)));

__device__ inline float bf_lo(unsigned u) { return __builtin_bit_cast(float, u << 16); }
__device__ inline float bf_hi(unsigned u) { return __builtin_bit_cast(float, u & 0xffff0000u); }
__device__ inline unsigned pack2(float a, float b) {
  unsigned lo = __builtin_bit_cast(unsigned short, (__bf16)a);
  unsigned hi = __builtin_bit_cast(unsigned short, (__bf16)b);
  return (hi << 16) | lo;
}
__device__ inline float silu(float v) { return v / (1.f + __expf(-v)); }

// ---------------------------------------------------------------------------
// Cost volume, channels-last bf16
// ---------------------------------------------------------------------------
__global__ __launch_bounds__(320)
void cv_cl_kernel(const float* __restrict__ fL, const float* __restrict__ fR,
                  __bf16* __restrict__ cv) {
  int w = threadIdx.x;
  int h = blockIdx.x % H_;
  int b = blockIdx.x / H_;
  int d0 = blockIdx.y * 6;
  const size_t rowbase = ((size_t)(b * C_) * H_ + h) * W_;
  float l[C_];
#pragma unroll
  for (int c = 0; c < C_; c++) l[c] = fL[rowbase + (size_t)c * HW_ + w];
  for (int dd = 0; dd < 6; dd++) {
    int d = d0 + dd;
    float s[8] = {0.f,0.f,0.f,0.f,0.f,0.f,0.f,0.f};
    if (w >= d) {
      const float* pr = fR + rowbase + (w - d);
#pragma unroll
      for (int c = 0; c < C_; c++) s[c >> 3] += l[c] * pr[(size_t)c * HW_];
    }
    b8 r;
#pragma unroll
    for (int g = 0; g < 8; g++) r[g] = (__bf16)(s[g] * 0.125f);
    *(b8*)(cv + ((size_t)((b * D_ + d) * H_ + h) * W_ + w) * 8) = r;
  }
}

// ---------------------------------------------------------------------------
// Weight prep: per-lane MFMA B-fragments. K order = taps x ci (ci fastest).
// ---------------------------------------------------------------------------
__global__ void wprep_kernel(const float* __restrict__ w1, const float* __restrict__ w2,
                             __bf16* __restrict__ wf1, __bf16* __restrict__ wf2) {
  int lane = threadIdx.x;      // 64 threads
  int co = lane & 15, kb = lane >> 4;
#pragma unroll
  for (int p = 0; p < 7; p++)
#pragma unroll
    for (int j = 0; j < 8; j++) {
      int kl = kb * 8 + j;
      int tap = p * 4 + (kl >> 3);
      int ci = kl & 7;
      float v = (tap <= 26) ? w1[(co * 8 + ci) * 27 + tap] : 0.f;
      wf1[(p * 64 + lane) * 8 + j] = (__bf16)v;
    }
#pragma unroll
  for (int p = 0; p < 14; p++)
#pragma unroll
    for (int j = 0; j < 8; j++) {
      int kl = kb * 8 + j;
      int tap = p * 2 + (kl >> 4);
      int ci = kl & 15;
      float v = (tap <= 26) ? w2[(co * 16 + ci) * 27 + tap] : 0.f;
      wf2[(p * 64 + lane) * 8 + j] = (__bf16)v;
    }
}

// ---------------------------------------------------------------------------
// 3x3x3 conv3d as implicit-GEMM MFMA with LDS-staged input halo.
// Block: 320 thr (5 waves) covers (b,d,h) x 160-wide half-row.
// LDS: [3dd][3hh][162pos][CIN] bf16 (46.7KB CIN=16 / 23.3KB CIN=8), zero-filled halo.
// Grid: B*D*H*2.
// ---------------------------------------------------------------------------
template <int CIN, int PAIRS>
__global__ __launch_bounds__(320)
void conv3d_mfma_kernel(const __bf16* __restrict__ in, const __bf16* __restrict__ wf,
                        __bf16* __restrict__ out) {
  __shared__ __align__(16) __bf16 li[9 * 162 * CIN];
  const int tid = threadIdx.x;
  int bid = blockIdx.x;                    // ((b*D + d)*H + h)*2 + wt
  const int wt = bid & 1; bid >>= 1;
  const int h = bid % H_;
  const int d = (bid / H_) % D_;
  const int b = bid / (H_ * D_);
  const int w0 = wt * 160;
  // --- stage halo (predicated, zero-fill) ---
  constexpr int VPE = CIN / 8;             // uint4 per entry
  for (int idx = tid; idx < 1458 * VPE; idx += 320) {
    int entry = idx / VPE, half = idx % VPE;
    int pos = entry % 162;
    int r = entry / 162;
    int hh = r % 3, dd = r / 3;
    int dg = d + dd - 1, hg = h + hh - 1, wg = w0 + pos - 1;
    uint4 v = make_uint4(0, 0, 0, 0);
    if ((unsigned)dg < (unsigned)D_ && (unsigned)hg < (unsigned)H_ && (unsigned)wg < (unsigned)W_)
      v = *(const uint4*)(in + ((size_t)((b * D_ + dg) * H_ + hg) * W_ + wg) * CIN + half * 8);
    *(uint4*)(li + (size_t)entry * CIN + half * 8) = v;
  }
  __syncthreads();
  // --- compute ---
  const int lane = tid & 63;
  const int wid = tid >> 6;
  const int m = lane & 15;
  const int tpp = 32 / CIN;                // taps per K-tile
  const int tapsel = (CIN == 16) ? (lane >> 5) : (lane >> 4);
  const int ci0 = (CIN == 16) ? ((lane >> 1) & 8) : 0;
  b8 wfr[PAIRS];
#pragma unroll
  for (int p = 0; p < PAIRS; p++) wfr[p] = *(const b8*)(wf + (p * 64 + lane) * 8);
  int loff[PAIRS];
#pragma unroll
  for (int p = 0; p < PAIRS; p++) {
    int tap = p * tpp + tapsel;
    if (tap > 26) tap = 26;                // dummy slot has zero weights
    int kd = tap / 9, kh = (tap / 3) % 3, kw = tap % 3;
    loff[p] = ((kd * 3 + kh) * 162 + kw) * CIN + ci0;
  }
  const int rowbase = ((b * D_ + d) * H_ + h) * W_ + w0;
  for (int t = 0; t < 2; t++) {
    const int m0 = (wid * 2 + t) * 16;
    const int lbase = (m0 + m) * CIN;
    f4 acc = {0.f, 0.f, 0.f, 0.f};
#pragma unroll
    for (int p = 0; p < PAIRS; p++) {
      b8 a = *(const b8*)(li + lbase + loff[p]);
      acc = __builtin_amdgcn_mfma_f32_16x16x32_bf16(a, wfr[p], acc, 0, 0, 0);
    }
    const int co = lane & 15;
    const int r0 = (lane >> 4) * 4;
    const int pos0 = rowbase + m0;
#pragma unroll
    for (int r = 0; r < 4; r++)
      out[(size_t)(pos0 + r0 + r) * 16 + co] = (__bf16)acc[r];
  }
}

// ---------------------------------------------------------------------------
// GN stats, channels-last bf16 [b][pos][16]
// ---------------------------------------------------------------------------
__global__ __launch_bounds__(256)
void stats_cl_kernel(const __bf16* __restrict__ x, double* __restrict__ st) {
  int b = blockIdx.y;
  float sg[8] = {0,0,0,0,0,0,0,0}, sq[8] = {0,0,0,0,0,0,0,0};
  for (int i = blockIdx.x * 256 + threadIdx.x; i < DHW_; i += gridDim.x * 256) {
    const uint4* p = (const uint4*)(x + ((size_t)b * DHW_ + i) * 16);
    uint4 q0 = p[0], q1 = p[1];
    unsigned us[8] = {q0.x, q0.y, q0.z, q0.w, q1.x, q1.y, q1.z, q1.w};
#pragma unroll
    for (int k = 0; k < 8; k++) {
      float v0 = bf_lo(us[k]), v1 = bf_hi(us[k]);
      sg[k] += v0 + v1;
      sq[k] += v0 * v0 + v1 * v1;
    }
  }
#pragma unroll
  for (int k = 0; k < 8; k++)
    for (int off = 32; off; off >>= 1) {
      sg[k] += __shfl_xor(sg[k], off, 64);
      sq[k] += __shfl_xor(sq[k], off, 64);
    }
  __shared__ float ls[4][16];
  int wid = threadIdx.x >> 6, lane = threadIdx.x & 63;
  if (lane == 0) {
#pragma unroll
    for (int k = 0; k < 8; k++) { ls[wid][k] = sg[k]; ls[wid][8 + k] = sq[k]; }
  }
  __syncthreads();
  if (threadIdx.x < 16) {
    float t = ls[0][threadIdx.x] + ls[1][threadIdx.x] + ls[2][threadIdx.x] + ls[3][threadIdx.x];
    int g = threadIdx.x & 7, which = threadIdx.x >> 3;
    atomicAdd(&st[(size_t)(b * 8 + g) * 2 + which], (double)t);
  }
}

// ---------------------------------------------------------------------------
// GN normalize + SiLU in place, channels-last bf16
// ---------------------------------------------------------------------------
__global__ __launch_bounds__(256)
void norm_cl_kernel(__bf16* __restrict__ x, const double* __restrict__ st,
                    const float* __restrict__ gamma, const float* __restrict__ beta,
                    double invN) {
  int b = blockIdx.y;
  __shared__ float scs[16], shs[16];
  if (threadIdx.x < 16) {
    int c = threadIdx.x, grp = c >> 1;
    double mean = st[(size_t)(b * 8 + grp) * 2] * invN;
    double var = st[(size_t)(b * 8 + grp) * 2 + 1] * invN - mean * mean;
    float sc = gamma[c] * rsqrtf((float)var + EPS_);
    scs[c] = sc;
    shs[c] = beta[c] - (float)mean * sc;
  }
  __syncthreads();
  float sc[16], sh[16];
#pragma unroll
  for (int c = 0; c < 16; c++) { sc[c] = scs[c]; sh[c] = shs[c]; }
  for (int i = blockIdx.x * 256 + threadIdx.x; i < DHW_; i += gridDim.x * 256) {
    uint4* p = (uint4*)(x + ((size_t)b * DHW_ + i) * 16);
    uint4 q0 = p[0], q1 = p[1];
    unsigned us[8] = {q0.x, q0.y, q0.z, q0.w, q1.x, q1.y, q1.z, q1.w};
    unsigned ro[8];
#pragma unroll
    for (int k = 0; k < 8; k++) {
      int c0 = 2 * k;
      float v0 = silu(bf_lo(us[k]) * sc[c0] + sh[c0]);
      float v1 = silu(bf_hi(us[k]) * sc[c0 + 1] + sh[c0 + 1]);
      ro[k] = pack2(v0, v1);
    }
    p[0] = make_uint4(ro[0], ro[1], ro[2], ro[3]);
    p[1] = make_uint4(ro[4], ro[5], ro[6], ro[7]);
  }
}

// ---------------------------------------------------------------------------
// conv3d #3 (16->1) + bias, LDS-tiled. Output tile: 3 d x 4 h x 64 w.
// ---------------------------------------------------------------------------
__global__ __launch_bounds__(256)
void conv3_tile_kernel(const __bf16* __restrict__ a2, const float* __restrict__ wt,
                       const float* __restrict__ bias, float* __restrict__ logits) {
  __shared__ __align__(16) __bf16 li[5 * 6 * 2 * 66 * 8];   // 63360 B
  __shared__ float lw[432];                                  // [tap][ci]
  int bid = blockIdx.x;
  int wtile = bid % 5; bid /= 5;
  int ht = bid % 40; bid /= 40;
  int dt = bid % 8; bid /= 8;
  int b = bid;
  const int d0 = dt * 3, h0 = ht * 4, w0 = wtile * 64;
  for (int i = threadIdx.x; i < 432; i += 256) {
    int tap = i >> 4, ci = i & 15;
    lw[i] = wt[ci * 27 + tap];
  }
  for (int idx = threadIdx.x; idx < 5 * 6 * 66; idx += 256) {
    int pos = idx % 66;
    int r = idx / 66;
    int hh = r % 6, dd = r / 6;
    int d = d0 + dd - 1, h = h0 + hh - 1, w = w0 + pos - 1;
    uint4 v0 = make_uint4(0, 0, 0, 0), v1 = v0;
    if ((unsigned)d < (unsigned)D_ && (unsigned)h < (unsigned)H_ && (unsigned)w < (unsigned)W_) {
      const uint4* p = (const uint4*)(a2 + ((size_t)(((b * D_ + d) * H_ + h) * W_ + w)) * 16);
      v0 = p[0];
      v1 = p[1];
    }
    int vb = ((dd * 6 + hh) * 2) * 66 + pos;       // half-0 vector index
    *(uint4*)(li + (size_t)vb * 8) = v0;
    *(uint4*)(li + (size_t)(vb + 66) * 8) = v1;    // half-1 plane
  }
  __syncthreads();
  const int ow = threadIdx.x & 63;
  const int oh = threadIdx.x >> 6;                 // 0..3 (uniform per wave)
  float acc[3] = {0.f, 0.f, 0.f};
  for (int kd = 0; kd < 3; kd++)
    for (int kh = 0; kh < 3; kh++)
      for (int kw = 0; kw < 3; kw++) {
        const int tap = kd * 9 + kh * 3 + kw;
        const float* wp = lw + tap * 16;
        float wv[16];
#pragma unroll
        for (int c = 0; c < 16; c++) wv[c] = wp[c];
        const int hh = oh + kh;
        const int pos = ow + kw;
#pragma unroll
        for (int od = 0; od < 3; od++) {
          const int dd = od + kd;
          const int vb = ((dd * 6 + hh) * 2) * 66 + pos;
          uint4 q0 = *(const uint4*)(li + (size_t)vb * 8);
          uint4 q1 = *(const uint4*)(li + (size_t)(vb + 66) * 8);
          acc[od] +=
            bf_lo(q0.x) * wv[0]  + bf_hi(q0.x) * wv[1]  + bf_lo(q0.y) * wv[2]  + bf_hi(q0.y) * wv[3] +
            bf_lo(q0.z) * wv[4]  + bf_hi(q0.z) * wv[5]  + bf_lo(q0.w) * wv[6]  + bf_hi(q0.w) * wv[7] +
            bf_lo(q1.x) * wv[8]  + bf_hi(q1.x) * wv[9]  + bf_lo(q1.y) * wv[10] + bf_hi(q1.y) * wv[11] +
            bf_lo(q1.z) * wv[12] + bf_hi(q1.z) * wv[13] + bf_lo(q1.w) * wv[14] + bf_hi(q1.w) * wv[15];
        }
      }
  const float bv = bias[0];
#pragma unroll
  for (int od = 0; od < 3; od++)
    logits[((size_t)(b * D_ + d0 + od) * H_ + (h0 + oh)) * W_ + w0 + ow] = acc[od] + bv;
}

// ---------------------------------------------------------------------------
// 3x3 conv2d, pad 1 (heads; fp32 channels-first), output-channel-split
// ---------------------------------------------------------------------------
template <int C0, int C1, int COUT, int COT, bool HASBIAS, bool ADD_DSA>
__global__ __launch_bounds__(320)
void conv2d_kernel(const float* __restrict__ in0, const float* __restrict__ in1,
                   const float* __restrict__ wt, const float* __restrict__ bias,
                   const float* __restrict__ dsa, float* __restrict__ out) {
  constexpr int CINT = C0 + C1;
  constexpr int CL = COUT / COT;           // channels per block
  __shared__ float lw[CL * CINT * 9];
  const int co0 = blockIdx.y * CL;
  for (int i = threadIdx.x; i < CL * CINT * 9; i += 320) lw[i] = wt[co0 * CINT * 9 + i];
  __syncthreads();
  int w = threadIdx.x;
  int h = blockIdx.x % H_;
  int b = blockIdx.x / H_;
  float acc[CL];
#pragma unroll
  for (int co = 0; co < CL; co++) acc[co] = 0.f;
  for (int kh = 0; kh < 3; kh++) {
    int hh = h + kh - 1;
    if (hh < 0 || hh >= H_) continue;
    for (int kw = 0; kw < 3; kw++) {
      int ww = w + kw - 1;
      if (ww < 0 || ww >= W_) continue;
#pragma unroll
      for (int ci = 0; ci < C0; ci++) {
        float v = in0[((size_t)(b * C0 + ci)) * HW_ + hh * W_ + ww];
        const float* lwp = lw + (ci * 3 + kh) * 3 + kw;
#pragma unroll
        for (int co = 0; co < CL; co++) acc[co] += v * lwp[co * CINT * 9];
      }
      if (C1 > 0) {
#pragma unroll
        for (int ci = 0; ci < (C1 > 0 ? C1 : 1); ci++) {
          float v = in1[((size_t)(b * C1 + ci)) * HW_ + hh * W_ + ww];
          const float* lwp = lw + ((C0 + ci) * 3 + kh) * 3 + kw;
#pragma unroll
          for (int co = 0; co < CL; co++) acc[co] += v * lwp[co * CINT * 9];
        }
      }
    }
  }
#pragma unroll
  for (int co = 0; co < CL; co++) {
    float r = acc[co];
    if (HASBIAS) r += bias[co0 + co];
    if (ADD_DSA) r += dsa[(size_t)b * HW_ + h * W_ + w];
    out[((size_t)(b * COUT + co0 + co)) * HW_ + h * W_ + w] = r;
  }
}

// ---------------------------------------------------------------------------
// Conv1d over flattened H*W axis — unchanged
// ---------------------------------------------------------------------------
__global__ __launch_bounds__(256)
void conv1d_kernel(const float* __restrict__ logits, const float* __restrict__ wt,
                   float* __restrict__ out) {
  __shared__ float lw[D_ * D_ * 3];
  for (int i = threadIdx.x; i < D_ * D_ * 3; i += 256) lw[i] = wt[i];
  __syncthreads();
  int idx = blockIdx.x * 256 + threadIdx.x;
  int b = idx / HW_;
  int i = idx % HW_;
  float acc[D_];
#pragma unroll
  for (int o = 0; o < D_; o++) acc[o] = 0.f;
  for (int k = 0; k < 3; k++) {
    int pos = i + k - 1;
    if (pos < 0 || pos >= HW_) continue;
#pragma unroll
    for (int din = 0; din < D_; din++) {
      float v = logits[((size_t)b * D_ + din) * HW_ + pos];
      const float* lwp = lw + din * 3 + k;
#pragma unroll
      for (int o = 0; o < D_; o++) acc[o] += v * lwp[o * D_ * 3];
    }
  }
#pragma unroll
  for (int o = 0; o < D_; o++) out[((size_t)b * D_ + o) * HW_ + i] = acc[o];
}

// ---------------------------------------------------------------------------
// GN stats fp32 channels-first (heads) — unchanged
// ---------------------------------------------------------------------------
__global__ __launch_bounds__(256)
void stats_kernel(const float* __restrict__ x, double* __restrict__ stats,
                  int Cc, int chg, size_t per_ch, int nchunk) {
  int tmp = blockIdx.x;
  int chunk = tmp % nchunk; tmp /= nchunk;
  int cig = tmp % chg; tmp /= chg;
  int grp = tmp % 8;
  int b = tmp / 8;
  int c = grp * chg + cig;
  size_t len = per_ch / nchunk;
  const float* p = x + ((size_t)b * Cc + c) * per_ch + (size_t)chunk * len;
  float s = 0.f, s2 = 0.f;
  for (size_t i = threadIdx.x; i < len; i += 256) {
    float v = p[i];
    s += v;
    s2 += v * v;
  }
  __shared__ double ls[256], ls2[256];
  ls[threadIdx.x] = (double)s;
  ls2[threadIdx.x] = (double)s2;
  __syncthreads();
  for (int off = 128; off > 0; off >>= 1) {
    if (threadIdx.x < off) {
      ls[threadIdx.x] += ls[threadIdx.x + off];
      ls2[threadIdx.x] += ls2[threadIdx.x + off];
    }
    __syncthreads();
  }
  if (threadIdx.x == 0) {
    atomicAdd(&stats[(size_t)(b * 8 + grp) * 2], ls[0]);
    atomicAdd(&stats[(size_t)(b * 8 + grp) * 2 + 1], ls2[0]);
  }
}

// norm+SiLU fp32 channels-first (heads) — unchanged
__global__ __launch_bounds__(256)
void norm_silu_f32o_kernel(const float* __restrict__ x, float* __restrict__ y,
                           const double* __restrict__ stats,
                           const float* __restrict__ gamma, const float* __restrict__ beta,
                           int chg, size_t per_ch, double invN) {
  int c = blockIdx.y;
  int b = blockIdx.z;
  int grp = c / chg;
  double s = stats[(size_t)(b * 8 + grp) * 2];
  double s2 = stats[(size_t)(b * 8 + grp) * 2 + 1];
  double mean_d = s * invN;
  double var_d = s2 * invN - mean_d * mean_d;
  float sc = gamma[c] / sqrtf((float)var_d + EPS_);
  float sh = beta[c] - (float)mean_d * sc;
  size_t base = ((size_t)b * gridDim.y + c) * per_ch;
  size_t chunk = (per_ch + gridDim.x - 1) / gridDim.x;
  size_t start = (size_t)blockIdx.x * chunk;
  size_t end = start + chunk;
  if (end > per_ch) end = per_ch;
  for (size_t i = start + threadIdx.x; i < end; i += 256) {
    float v = x[base + i] * sc + sh;
    y[base + i] = v / (1.f + __expf(-v));
  }
}

// ---------------------------------------------------------------------------
// Softmax over D + soft-argmin + confidence — unchanged
// ---------------------------------------------------------------------------
__global__ __launch_bounds__(320)
void softmax_kernel(const float* __restrict__ logits, float* __restrict__ dsa,
                    float* __restrict__ conf) {
  int w = threadIdx.x;
  int h = blockIdx.x % H_;
  int b = blockIdx.x / H_;
  size_t base = ((size_t)b * D_) * HW_ + h * W_ + w;
  float v[D_];
  float m = -1e30f;
#pragma unroll
  for (int d = 0; d < D_; d++) {
    v[d] = logits[base + (size_t)d * HW_];
    m = fmaxf(m, v[d]);
  }
  float s = 0.f, wd = 0.f;
#pragma unroll
  for (int d = 0; d < D_; d++) {
    float e = __expf(v[d] - m);
    s += e;
    wd += (float)d * e;
  }
  float inv = 1.f / s;
  dsa[(size_t)b * HW_ + h * W_ + w] = wd * inv;
  conf[(size_t)b * HW_ + h * W_ + w] = inv;  // max prob
}

// ---------------------------------------------------------------------------

extern "C" void kernel_launch(void* const* d_in, const int* in_sizes, int n_in,
                              void* d_out, int out_size, void* d_ws, size_t ws_size,
                              hipStream_t stream) {
  const float* fL = (const float*)d_in[0];
  const float* fR = (const float*)d_in[1];
  const float* agg_w1 = (const float*)d_in[2];
  const float* agg_g1 = (const float*)d_in[3];
  const float* agg_b1 = (const float*)d_in[4];
  const float* agg_w2 = (const float*)d_in[5];
  const float* agg_g2 = (const float*)d_in[6];
  const float* agg_b2 = (const float*)d_in[7];
  const float* agg_w3 = (const float*)d_in[8];
  const float* agg_bias3 = (const float*)d_in[9];
  const float* feat_w = (const float*)d_in[10];
  const float* feat_g = (const float*)d_in[11];
  const float* feat_b = (const float*)d_in[12];
  const float* apc_w = (const float*)d_in[13];
  const float* reg_w1 = (const float*)d_in[14];
  const float* reg_g1 = (const float*)d_in[15];
  const float* reg_b1 = (const float*)d_in[16];
  const float* reg_w2 = (const float*)d_in[17];
  const float* reg_bias2 = (const float*)d_in[18];

  char* wsb = (char*)d_ws;
  // Region A [0, 78.6MB): a1 (bf16 CL); after conv2 consumed it, reused for
  // small fp32 buffers. Region B [78.6MB, 157.3MB): cv then a2 (cv dead).
  constexpr size_t REG = 78643200ull;
  __bf16* a1 = (__bf16*)wsb;
  __bf16* cvb = (__bf16*)(wsb + REG);
  __bf16* a2 = (__bf16*)(wsb + REG);
  float* logits = (float*)wsb;                   // 2,457,600 f
  float* apc = logits + 2457600;                 // 2,457,600 f
  float* h2 = apc + 2457600;                     // 3,276,800 f
  float* dsa = h2 + 3276800;                     //   102,400 f
  float* featraw = dsa + 102400;                 // 1,638,400 f
  __bf16* wf1 = (__bf16*)(wsb + 2 * REG);        // 3584 elems
  __bf16* wf2 = wf1 + 3584;                      // 7168 elems
  double* stats = (double*)(wsb + 2 * REG + 21504);  // 128 doubles

  float* out = (float*)d_out;
  float* out_dinit = out;                        // [B,1,H,W]
  float* out_sx = out + 102400;                  // zeros (sx, sy)
  float* out_feat = out + 307200;                // [B,16,H,W]
  float* out_conf = out + 1945600;               // [B,1,H,W]

  hipMemsetAsync(stats, 0, 128 * sizeof(double), stream);
  hipMemsetAsync(out_sx, 0, 2 * 102400 * sizeof(float), stream);

  // weight fragments
  wprep_kernel<<<1, 64, 0, stream>>>(agg_w1, agg_w2, wf1, wf2);

  // cost volume (channels-last bf16)
  cv_cl_kernel<<<dim3(B_ * H_, 4), 320, 0, stream>>>(fL, fR, cvb);

  // agg conv1 (8->16) MFMA+LDS ; GN ; SiLU
  conv3d_mfma_kernel<8, 7><<<B_ * D_ * H_ * 2, 320, 0, stream>>>(cvb, wf1, a1);
  stats_cl_kernel<<<dim3(256, B_), 256, 0, stream>>>(a1, stats + 0);
  norm_cl_kernel<<<dim3(512, B_), 256, 0, stream>>>(a1, stats + 0, agg_g1, agg_b1,
                                                    1.0 / (2.0 * DHW_));

  // agg conv2 (16->16) MFMA+LDS ; GN ; SiLU
  conv3d_mfma_kernel<16, 14><<<B_ * D_ * H_ * 2, 320, 0, stream>>>(a1, wf2, a2);
  stats_cl_kernel<<<dim3(256, B_), 256, 0, stream>>>(a2, stats + 32);
  norm_cl_kernel<<<dim3(512, B_), 256, 0, stream>>>(a2, stats + 32, agg_g2, agg_b2,
                                                    1.0 / (2.0 * DHW_));

  // agg conv3 (16->1) + bias -> logits (fp32, [B,D,H,W]), LDS-tiled
  conv3_tile_kernel<<<3200, 256, 0, stream>>>(a2, agg_w3, agg_bias3, logits);

  // softmax -> dsa (ws), conf (out)
  softmax_kernel<<<B_ * H_, 320, 0, stream>>>(logits, dsa, out_conf);

  // feat head: conv2d(64->16, 2 co-tiles) ; GN ; SiLU -> out_feat
  conv2d_kernel<C_, 0, 16, 2, false, false><<<dim3(B_ * H_, 2), 320, 0, stream>>>(
      fL, nullptr, feat_w, nullptr, nullptr, featraw);
  stats_kernel<<<B_ * 8 * 2 * 8, 256, 0, stream>>>(featraw, stats + 64, 16, 2, (size_t)HW_, 8);
  norm_silu_f32o_kernel<<<dim3(50, 16, B_), 256, 0, stream>>>(featraw, out_feat, stats + 64,
                                                              feat_g, feat_b, 2, (size_t)HW_,
                                                              1.0 / (2.0 * HW_));

  // apc conv1d on flattened logits
  conv1d_kernel<<<(B_ * HW_) / 256, 256, 0, stream>>>(logits, apc_w, apc);

  // regression head conv1 (24+16 -> 32, 4 co-tiles) ; GN ; SiLU
  conv2d_kernel<D_, 16, 32, 4, false, false><<<dim3(B_ * H_, 4), 320, 0, stream>>>(
      apc, out_feat, reg_w1, nullptr, nullptr, h2);
  stats_kernel<<<B_ * 8 * 4 * 8, 256, 0, stream>>>(h2, stats + 96, 32, 4, (size_t)HW_, 8);
  norm_silu_f32o_kernel<<<dim3(50, 32, B_), 256, 0, stream>>>(h2, h2, stats + 96, reg_g1, reg_b1,
                                                              4, (size_t)HW_, 1.0 / (4.0 * HW_));

  // regression conv2 (32->1) + bias + d_sa -> d_init
  conv2d_kernel<32, 0, 1, 1, true, true><<<dim3(B_ * H_, 1), 320, 0, stream>>>(
      h2, nullptr, reg_w2, reg_bias2, dsa, out_dinit);
}

// Round 12
// 725.248 us; speedup vs baseline: 3.5690x; 1.1589x over previous
//
#include <hip/hip_runtime.h>
#include <hip/hip_bf16.h>
#include <math.h>

// Problem constants
constexpr int B_ = 2;
constexpr int C_ = 64;
constexpr int H_ = 160;
constexpr int W_ = 320;
constexpr int G_ = 8;       // correlation groups
constexpr int D_ = 24;      // max disparity
constexpr int HW_ = H_ * W_;        // 51200
constexpr int DHW_ = D_ * HW_;      // 1228800
constexpr float EPS_ = 1e-5f;

typedef __bf16 b8 __attribute__((ext_vector_type(8)));
typedef float  f4 __attribute__((ext_vector_type(4)));

__device__ inline float bf_lo(unsigned u) { return __builtin_bit_cast(float, u << 16); }
__device__ inline float bf_hi(unsigned u) { return __builtin_bit_cast(float, u & 0xffff0000u); }
__device__ inline unsigned pack2(float a, float b) {
  unsigned lo = __builtin_bit_cast(unsigned short, (__bf16)a);
  unsigned hi = __builtin_bit_cast(unsigned short, (__bf16)b);
  return (hi << 16) | lo;
}
__device__ inline float silu(float v) { return v / (1.f + __expf(-v)); }

// ---------------------------------------------------------------------------
// Cost volume, channels-last bf16
// ---------------------------------------------------------------------------
__global__ __launch_bounds__(320)
void cv_cl_kernel(const float* __restrict__ fL, const float* __restrict__ fR,
                  __bf16* __restrict__ cv) {
  int w = threadIdx.x;
  int h = blockIdx.x % H_;
  int b = blockIdx.x / H_;
  int d0 = blockIdx.y * 6;
  const size_t rowbase = ((size_t)(b * C_) * H_ + h) * W_;
  float l[C_];
#pragma unroll
  for (int c = 0; c < C_; c++) l[c] = fL[rowbase + (size_t)c * HW_ + w];
  for (int dd = 0; dd < 6; dd++) {
    int d = d0 + dd;
    float s[8] = {0.f,0.f,0.f,0.f,0.f,0.f,0.f,0.f};
    if (w >= d) {
      const float* pr = fR + rowbase + (w - d);
#pragma unroll
      for (int c = 0; c < C_; c++) s[c >> 3] += l[c] * pr[(size_t)c * HW_];
    }
    b8 r;
#pragma unroll
    for (int g = 0; g < 8; g++) r[g] = (__bf16)(s[g] * 0.125f);
    *(b8*)(cv + ((size_t)((b * D_ + d) * H_ + h) * W_ + w) * 8) = r;
  }
}

// ---------------------------------------------------------------------------
// Weight prep: per-lane MFMA B-fragments. K order = taps x ci (ci fastest).
// ---------------------------------------------------------------------------
__global__ void wprep_kernel(const float* __restrict__ w1, const float* __restrict__ w2,
                             __bf16* __restrict__ wf1, __bf16* __restrict__ wf2) {
  int lane = threadIdx.x;      // 64 threads
  int co = lane & 15, kb = lane >> 4;
#pragma unroll
  for (int p = 0; p < 7; p++)
#pragma unroll
    for (int j = 0; j < 8; j++) {
      int kl = kb * 8 + j;
      int tap = p * 4 + (kl >> 3);
      int ci = kl & 7;
      float v = (tap <= 26) ? w1[(co * 8 + ci) * 27 + tap] : 0.f;
      wf1[(p * 64 + lane) * 8 + j] = (__bf16)v;
    }
#pragma unroll
  for (int p = 0; p < 14; p++)
#pragma unroll
    for (int j = 0; j < 8; j++) {
      int kl = kb * 8 + j;
      int tap = p * 2 + (kl >> 4);
      int ci = kl & 15;
      float v = (tap <= 26) ? w2[(co * 16 + ci) * 27 + tap] : 0.f;
      wf2[(p * 64 + lane) * 8 + j] = (__bf16)v;
    }
}

// ---------------------------------------------------------------------------
// 3x3x3 conv3d as implicit-GEMM MFMA, 3D-tiled LDS staging.
// Output tile: 3d x 4h x 64w (768 positions = 48 M-tiles of 16).
// LDS halo [5dd][6hh][66pos][CIN] bf16: 63.4KB (CIN=16) / 31.7KB (CIN=8).
// Block 256 thr (4 waves, 12 M-tiles each). Grid: b(2) x dt(8) x ht(40) x wt(5).
// ---------------------------------------------------------------------------
template <int CIN, int PAIRS>
__global__ __launch_bounds__(256)
void conv3d_mfma_kernel(const __bf16* __restrict__ in, const __bf16* __restrict__ wf,
                        __bf16* __restrict__ out) {
  __shared__ __align__(16) __bf16 li[5 * 6 * 66 * CIN];
  const int tid = threadIdx.x;
  int bid = blockIdx.x;
  int wtile = bid % 5; bid /= 5;
  int ht = bid % 40; bid /= 40;
  int dt = bid % 8; bid /= 8;
  const int b = bid;
  const int d0 = dt * 3, h0 = ht * 4, w0 = wtile * 64;
  // --- stage halo (predicated, zero-fill), proven conv3_tile index math ---
  constexpr int VPE = CIN / 8;             // uint4 per entry
  for (int idx = tid; idx < 1980 * VPE; idx += 256) {
    int entry = idx / VPE, half = idx % VPE;
    int pos = entry % 66;
    int r = entry / 66;
    int hh = r % 6, dd = r / 6;
    int dg = d0 + dd - 1, hg = h0 + hh - 1, wg = w0 + pos - 1;
    uint4 v = make_uint4(0, 0, 0, 0);
    if ((unsigned)dg < (unsigned)D_ && (unsigned)hg < (unsigned)H_ && (unsigned)wg < (unsigned)W_)
      v = *(const uint4*)(in + ((size_t)((b * D_ + dg) * H_ + hg) * W_ + wg) * CIN + half * 8);
    *(uint4*)(li + (size_t)entry * CIN + half * 8) = v;
  }
  __syncthreads();
  // --- compute ---
  const int lane = tid & 63;
  const int wid = tid >> 6;
  const int m = lane & 15;
  const int tpp = 32 / CIN;                // taps per K-tile
  const int tapsel = (CIN == 16) ? (lane >> 5) : (lane >> 4);
  const int ci0 = (CIN == 16) ? ((lane >> 1) & 8) : 0;
  b8 wfr[PAIRS];
#pragma unroll
  for (int p = 0; p < PAIRS; p++) wfr[p] = *(const b8*)(wf + (p * 64 + lane) * 8);
  int loff[PAIRS];
#pragma unroll
  for (int p = 0; p < PAIRS; p++) {
    int tap = p * tpp + tapsel;
    if (tap > 26) tap = 26;                // dummy slot has zero weights
    int kd = tap / 9, kh = (tap / 3) % 3, kw = tap % 3;
    loff[p] = ((kd * 6 + kh) * 66 + kw) * CIN + ci0;
  }
  const int co = lane & 15;
  const int r0 = (lane >> 4) * 4;
#pragma unroll 4
  for (int t = 0; t < 12; t++) {
    const int mt = wid * 12 + t;           // 0..47
    const int od = mt >> 4;
    const int rem = mt & 15;
    const int oh = rem >> 2, wq = rem & 3;
    const int lbase = ((od * 6 + oh) * 66 + wq * 16 + m) * CIN;
    f4 acc = {0.f, 0.f, 0.f, 0.f};
#pragma unroll
    for (int p = 0; p < PAIRS; p++) {
      b8 a = *(const b8*)(li + lbase + loff[p]);
      acc = __builtin_amdgcn_mfma_f32_16x16x32_bf16(a, wfr[p], acc, 0, 0, 0);
    }
    const int wbase = ((b * D_ + d0 + od) * H_ + h0 + oh) * W_ + w0 + wq * 16;
#pragma unroll
    for (int r = 0; r < 4; r++)
      out[(size_t)(wbase + r0 + r) * 16 + co] = (__bf16)acc[r];
  }
}

// ---------------------------------------------------------------------------
// GN stats, channels-last bf16 [b][pos][16]
// ---------------------------------------------------------------------------
__global__ __launch_bounds__(256)
void stats_cl_kernel(const __bf16* __restrict__ x, double* __restrict__ st) {
  int b = blockIdx.y;
  float sg[8] = {0,0,0,0,0,0,0,0}, sq[8] = {0,0,0,0,0,0,0,0};
  for (int i = blockIdx.x * 256 + threadIdx.x; i < DHW_; i += gridDim.x * 256) {
    const uint4* p = (const uint4*)(x + ((size_t)b * DHW_ + i) * 16);
    uint4 q0 = p[0], q1 = p[1];
    unsigned us[8] = {q0.x, q0.y, q0.z, q0.w, q1.x, q1.y, q1.z, q1.w};
#pragma unroll
    for (int k = 0; k < 8; k++) {
      float v0 = bf_lo(us[k]), v1 = bf_hi(us[k]);
      sg[k] += v0 + v1;
      sq[k] += v0 * v0 + v1 * v1;
    }
  }
#pragma unroll
  for (int k = 0; k < 8; k++)
    for (int off = 32; off; off >>= 1) {
      sg[k] += __shfl_xor(sg[k], off, 64);
      sq[k] += __shfl_xor(sq[k], off, 64);
    }
  __shared__ float ls[4][16];
  int wid = threadIdx.x >> 6, lane = threadIdx.x & 63;
  if (lane == 0) {
#pragma unroll
    for (int k = 0; k < 8; k++) { ls[wid][k] = sg[k]; ls[wid][8 + k] = sq[k]; }
  }
  __syncthreads();
  if (threadIdx.x < 16) {
    float t = ls[0][threadIdx.x] + ls[1][threadIdx.x] + ls[2][threadIdx.x] + ls[3][threadIdx.x];
    int g = threadIdx.x & 7, which = threadIdx.x >> 3;
    atomicAdd(&st[(size_t)(b * 8 + g) * 2 + which], (double)t);
  }
}

// ---------------------------------------------------------------------------
// GN normalize + SiLU in place, channels-last bf16
// ---------------------------------------------------------------------------
__global__ __launch_bounds__(256)
void norm_cl_kernel(__bf16* __restrict__ x, const double* __restrict__ st,
                    const float* __restrict__ gamma, const float* __restrict__ beta,
                    double invN) {
  int b = blockIdx.y;
  __shared__ float scs[16], shs[16];
  if (threadIdx.x < 16) {
    int c = threadIdx.x, grp = c >> 1;
    double mean = st[(size_t)(b * 8 + grp) * 2] * invN;
    double var = st[(size_t)(b * 8 + grp) * 2 + 1] * invN - mean * mean;
    float sc = gamma[c] * rsqrtf((float)var + EPS_);
    scs[c] = sc;
    shs[c] = beta[c] - (float)mean * sc;
  }
  __syncthreads();
  float sc[16], sh[16];
#pragma unroll
  for (int c = 0; c < 16; c++) { sc[c] = scs[c]; sh[c] = shs[c]; }
  for (int i = blockIdx.x * 256 + threadIdx.x; i < DHW_; i += gridDim.x * 256) {
    uint4* p = (uint4*)(x + ((size_t)b * DHW_ + i) * 16);
    uint4 q0 = p[0], q1 = p[1];
    unsigned us[8] = {q0.x, q0.y, q0.z, q0.w, q1.x, q1.y, q1.z, q1.w};
    unsigned ro[8];
#pragma unroll
    for (int k = 0; k < 8; k++) {
      int c0 = 2 * k;
      float v0 = silu(bf_lo(us[k]) * sc[c0] + sh[c0]);
      float v1 = silu(bf_hi(us[k]) * sc[c0 + 1] + sh[c0 + 1]);
      ro[k] = pack2(v0, v1);
    }
    p[0] = make_uint4(ro[0], ro[1], ro[2], ro[3]);
    p[1] = make_uint4(ro[4], ro[5], ro[6], ro[7]);
  }
}

// ---------------------------------------------------------------------------
// conv3d #3 (16->1) + bias, LDS-tiled. Output tile: 3 d x 4 h x 64 w.
// ---------------------------------------------------------------------------
__global__ __launch_bounds__(256)
void conv3_tile_kernel(const __bf16* __restrict__ a2, const float* __restrict__ wt,
                       const float* __restrict__ bias, float* __restrict__ logits) {
  __shared__ __align__(16) __bf16 li[5 * 6 * 2 * 66 * 8];   // 63360 B
  __shared__ float lw[432];                                  // [tap][ci]
  int bid = blockIdx.x;
  int wtile = bid % 5; bid /= 5;
  int ht = bid % 40; bid /= 40;
  int dt = bid % 8; bid /= 8;
  int b = bid;
  const int d0 = dt * 3, h0 = ht * 4, w0 = wtile * 64;
  for (int i = threadIdx.x; i < 432; i += 256) {
    int tap = i >> 4, ci = i & 15;
    lw[i] = wt[ci * 27 + tap];
  }
  for (int idx = threadIdx.x; idx < 5 * 6 * 66; idx += 256) {
    int pos = idx % 66;
    int r = idx / 66;
    int hh = r % 6, dd = r / 6;
    int d = d0 + dd - 1, h = h0 + hh - 1, w = w0 + pos - 1;
    uint4 v0 = make_uint4(0, 0, 0, 0), v1 = v0;
    if ((unsigned)d < (unsigned)D_ && (unsigned)h < (unsigned)H_ && (unsigned)w < (unsigned)W_) {
      const uint4* p = (const uint4*)(a2 + ((size_t)(((b * D_ + d) * H_ + h) * W_ + w)) * 16);
      v0 = p[0];
      v1 = p[1];
    }
    int vb = ((dd * 6 + hh) * 2) * 66 + pos;       // half-0 vector index
    *(uint4*)(li + (size_t)vb * 8) = v0;
    *(uint4*)(li + (size_t)(vb + 66) * 8) = v1;    // half-1 plane
  }
  __syncthreads();
  const int ow = threadIdx.x & 63;
  const int oh = threadIdx.x >> 6;                 // 0..3 (uniform per wave)
  float acc[3] = {0.f, 0.f, 0.f};
  for (int kd = 0; kd < 3; kd++)
    for (int kh = 0; kh < 3; kh++)
      for (int kw = 0; kw < 3; kw++) {
        const int tap = kd * 9 + kh * 3 + kw;
        const float* wp = lw + tap * 16;
        float wv[16];
#pragma unroll
        for (int c = 0; c < 16; c++) wv[c] = wp[c];
        const int hh = oh + kh;
        const int pos = ow + kw;
#pragma unroll
        for (int od = 0; od < 3; od++) {
          const int dd = od + kd;
          const int vb = ((dd * 6 + hh) * 2) * 66 + pos;
          uint4 q0 = *(const uint4*)(li + (size_t)vb * 8);
          uint4 q1 = *(const uint4*)(li + (size_t)(vb + 66) * 8);
          acc[od] +=
            bf_lo(q0.x) * wv[0]  + bf_hi(q0.x) * wv[1]  + bf_lo(q0.y) * wv[2]  + bf_hi(q0.y) * wv[3] +
            bf_lo(q0.z) * wv[4]  + bf_hi(q0.z) * wv[5]  + bf_lo(q0.w) * wv[6]  + bf_hi(q0.w) * wv[7] +
            bf_lo(q1.x) * wv[8]  + bf_hi(q1.x) * wv[9]  + bf_lo(q1.y) * wv[10] + bf_hi(q1.y) * wv[11] +
            bf_lo(q1.z) * wv[12] + bf_hi(q1.z) * wv[13] + bf_lo(q1.w) * wv[14] + bf_hi(q1.w) * wv[15];
        }
      }
  const float bv = bias[0];
#pragma unroll
  for (int od = 0; od < 3; od++)
    logits[((size_t)(b * D_ + d0 + od) * H_ + (h0 + oh)) * W_ + w0 + ow] = acc[od] + bv;
}

// ---------------------------------------------------------------------------
// 3x3 conv2d, pad 1 (heads; fp32 channels-first), output-channel-split
// ---------------------------------------------------------------------------
template <int C0, int C1, int COUT, int COT, bool HASBIAS, bool ADD_DSA>
__global__ __launch_bounds__(320)
void conv2d_kernel(const float* __restrict__ in0, const float* __restrict__ in1,
                   const float* __restrict__ wt, const float* __restrict__ bias,
                   const float* __restrict__ dsa, float* __restrict__ out) {
  constexpr int CINT = C0 + C1;
  constexpr int CL = COUT / COT;           // channels per block
  __shared__ float lw[CL * CINT * 9];
  const int co0 = blockIdx.y * CL;
  for (int i = threadIdx.x; i < CL * CINT * 9; i += 320) lw[i] = wt[co0 * CINT * 9 + i];
  __syncthreads();
  int w = threadIdx.x;
  int h = blockIdx.x % H_;
  int b = blockIdx.x / H_;
  float acc[CL];
#pragma unroll
  for (int co = 0; co < CL; co++) acc[co] = 0.f;
  for (int kh = 0; kh < 3; kh++) {
    int hh = h + kh - 1;
    if (hh < 0 || hh >= H_) continue;
    for (int kw = 0; kw < 3; kw++) {
      int ww = w + kw - 1;
      if (ww < 0 || ww >= W_) continue;
#pragma unroll
      for (int ci = 0; ci < C0; ci++) {
        float v = in0[((size_t)(b * C0 + ci)) * HW_ + hh * W_ + ww];
        const float* lwp = lw + (ci * 3 + kh) * 3 + kw;
#pragma unroll
        for (int co = 0; co < CL; co++) acc[co] += v * lwp[co * CINT * 9];
      }
      if (C1 > 0) {
#pragma unroll
        for (int ci = 0; ci < (C1 > 0 ? C1 : 1); ci++) {
          float v = in1[((size_t)(b * C1 + ci)) * HW_ + hh * W_ + ww];
          const float* lwp = lw + ((C0 + ci) * 3 + kh) * 3 + kw;
#pragma unroll
          for (int co = 0; co < CL; co++) acc[co] += v * lwp[co * CINT * 9];
        }
      }
    }
  }
#pragma unroll
  for (int co = 0; co < CL; co++) {
    float r = acc[co];
    if (HASBIAS) r += bias[co0 + co];
    if (ADD_DSA) r += dsa[(size_t)b * HW_ + h * W_ + w];
    out[((size_t)(b * COUT + co0 + co)) * HW_ + h * W_ + w] = r;
  }
}

// ---------------------------------------------------------------------------
// Conv1d over flattened H*W axis — unchanged
// ---------------------------------------------------------------------------
__global__ __launch_bounds__(256)
void conv1d_kernel(const float* __restrict__ logits, const float* __restrict__ wt,
                   float* __restrict__ out) {
  __shared__ float lw[D_ * D_ * 3];
  for (int i = threadIdx.x; i < D_ * D_ * 3; i += 256) lw[i] = wt[i];
  __syncthreads();
  int idx = blockIdx.x * 256 + threadIdx.x;
  int b = idx / HW_;
  int i = idx % HW_;
  float acc[D_];
#pragma unroll
  for (int o = 0; o < D_; o++) acc[o] = 0.f;
  for (int k = 0; k < 3; k++) {
    int pos = i + k - 1;
    if (pos < 0 || pos >= HW_) continue;
#pragma unroll
    for (int din = 0; din < D_; din++) {
      float v = logits[((size_t)b * D_ + din) * HW_ + pos];
      const float* lwp = lw + din * 3 + k;
#pragma unroll
      for (int o = 0; o < D_; o++) acc[o] += v * lwp[o * D_ * 3];
    }
  }
#pragma unroll
  for (int o = 0; o < D_; o++) out[((size_t)b * D_ + o) * HW_ + i] = acc[o];
}

// ---------------------------------------------------------------------------
// GN stats fp32 channels-first (heads) — unchanged
// ---------------------------------------------------------------------------
__global__ __launch_bounds__(256)
void stats_kernel(const float* __restrict__ x, double* __restrict__ stats,
                  int Cc, int chg, size_t per_ch, int nchunk) {
  int tmp = blockIdx.x;
  int chunk = tmp % nchunk; tmp /= nchunk;
  int cig = tmp % chg; tmp /= chg;
  int grp = tmp % 8;
  int b = tmp / 8;
  int c = grp * chg + cig;
  size_t len = per_ch / nchunk;
  const float* p = x + ((size_t)b * Cc + c) * per_ch + (size_t)chunk * len;
  float s = 0.f, s2 = 0.f;
  for (size_t i = threadIdx.x; i < len; i += 256) {
    float v = p[i];
    s += v;
    s2 += v * v;
  }
  __shared__ double ls[256], ls2[256];
  ls[threadIdx.x] = (double)s;
  ls2[threadIdx.x] = (double)s2;
  __syncthreads();
  for (int off = 128; off > 0; off >>= 1) {
    if (threadIdx.x < off) {
      ls[threadIdx.x] += ls[threadIdx.x + off];
      ls2[threadIdx.x] += ls2[threadIdx.x + off];
    }
    __syncthreads();
  }
  if (threadIdx.x == 0) {
    atomicAdd(&stats[(size_t)(b * 8 + grp) * 2], ls[0]);
    atomicAdd(&stats[(size_t)(b * 8 + grp) * 2 + 1], ls2[0]);
  }
}

// norm+SiLU fp32 channels-first (heads) — unchanged
__global__ __launch_bounds__(256)
void norm_silu_f32o_kernel(const float* __restrict__ x, float* __restrict__ y,
                           const double* __restrict__ stats,
                           const float* __restrict__ gamma, const float* __restrict__ beta,
                           int chg, size_t per_ch, double invN) {
  int c = blockIdx.y;
  int b = blockIdx.z;
  int grp = c / chg;
  double s = stats[(size_t)(b * 8 + grp) * 2];
  double s2 = stats[(size_t)(b * 8 + grp) * 2 + 1];
  double mean_d = s * invN;
  double var_d = s2 * invN - mean_d * mean_d;
  float sc = gamma[c] / sqrtf((float)var_d + EPS_);
  float sh = beta[c] - (float)mean_d * sc;
  size_t base = ((size_t)b * gridDim.y + c) * per_ch;
  size_t chunk = (per_ch + gridDim.x - 1) / gridDim.x;
  size_t start = (size_t)blockIdx.x * chunk;
  size_t end = start + chunk;
  if (end > per_ch) end = per_ch;
  for (size_t i = start + threadIdx.x; i < end; i += 256) {
    float v = x[base + i] * sc + sh;
    y[base + i] = v / (1.f + __expf(-v));
  }
}

// ---------------------------------------------------------------------------
// Softmax over D + soft-argmin + confidence — unchanged
// ---------------------------------------------------------------------------
__global__ __launch_bounds__(320)
void softmax_kernel(const float* __restrict__ logits, float* __restrict__ dsa,
                    float* __restrict__ conf) {
  int w = threadIdx.x;
  int h = blockIdx.x % H_;
  int b = blockIdx.x / H_;
  size_t base = ((size_t)b * D_) * HW_ + h * W_ + w;
  float v[D_];
  float m = -1e30f;
#pragma unroll
  for (int d = 0; d < D_; d++) {
    v[d] = logits[base + (size_t)d * HW_];
    m = fmaxf(m, v[d]);
  }
  float s = 0.f, wd = 0.f;
#pragma unroll
  for (int d = 0; d < D_; d++) {
    float e = __expf(v[d] - m);
    s += e;
    wd += (float)d * e;
  }
  float inv = 1.f / s;
  dsa[(size_t)b * HW_ + h * W_ + w] = wd * inv;
  conf[(size_t)b * HW_ + h * W_ + w] = inv;  // max prob
}

// ---------------------------------------------------------------------------

extern "C" void kernel_launch(void* const* d_in, const int* in_sizes, int n_in,
                              void* d_out, int out_size, void* d_ws, size_t ws_size,
                              hipStream_t stream) {
  const float* fL = (const float*)d_in[0];
  const float* fR = (const float*)d_in[1];
  const float* agg_w1 = (const float*)d_in[2];
  const float* agg_g1 = (const float*)d_in[3];
  const float* agg_b1 = (const float*)d_in[4];
  const float* agg_w2 = (const float*)d_in[5];
  const float* agg_g2 = (const float*)d_in[6];
  const float* agg_b2 = (const float*)d_in[7];
  const float* agg_w3 = (const float*)d_in[8];
  const float* agg_bias3 = (const float*)d_in[9];
  const float* feat_w = (const float*)d_in[10];
  const float* feat_g = (const float*)d_in[11];
  const float* feat_b = (const float*)d_in[12];
  const float* apc_w = (const float*)d_in[13];
  const float* reg_w1 = (const float*)d_in[14];
  const float* reg_g1 = (const float*)d_in[15];
  const float* reg_b1 = (const float*)d_in[16];
  const float* reg_w2 = (const float*)d_in[17];
  const float* reg_bias2 = (const float*)d_in[18];

  char* wsb = (char*)d_ws;
  // Region A [0, 78.6MB): a1 (bf16 CL); after conv2 consumed it, reused for
  // small fp32 buffers. Region B [78.6MB, 157.3MB): cv then a2 (cv dead).
  constexpr size_t REG = 78643200ull;
  __bf16* a1 = (__bf16*)wsb;
  __bf16* cvb = (__bf16*)(wsb + REG);
  __bf16* a2 = (__bf16*)(wsb + REG);
  float* logits = (float*)wsb;                   // 2,457,600 f
  float* apc = logits + 2457600;                 // 2,457,600 f
  float* h2 = apc + 2457600;                     // 3,276,800 f
  float* dsa = h2 + 3276800;                     //   102,400 f
  float* featraw = dsa + 102400;                 // 1,638,400 f
  __bf16* wf1 = (__bf16*)(wsb + 2 * REG);        // 3584 elems
  __bf16* wf2 = wf1 + 3584;                      // 7168 elems
  double* stats = (double*)(wsb + 2 * REG + 21504);  // 128 doubles

  float* out = (float*)d_out;
  float* out_dinit = out;                        // [B,1,H,W]
  float* out_sx = out + 102400;                  // zeros (sx, sy)
  float* out_feat = out + 307200;                // [B,16,H,W]
  float* out_conf = out + 1945600;               // [B,1,H,W]

  hipMemsetAsync(stats, 0, 128 * sizeof(double), stream);
  hipMemsetAsync(out_sx, 0, 2 * 102400 * sizeof(float), stream);

  // weight fragments
  wprep_kernel<<<1, 64, 0, stream>>>(agg_w1, agg_w2, wf1, wf2);

  // cost volume (channels-last bf16)
  cv_cl_kernel<<<dim3(B_ * H_, 4), 320, 0, stream>>>(fL, fR, cvb);

  // agg conv1 (8->16) MFMA 3D-tile ; GN ; SiLU
  conv3d_mfma_kernel<8, 7><<<3200, 256, 0, stream>>>(cvb, wf1, a1);
  stats_cl_kernel<<<dim3(256, B_), 256, 0, stream>>>(a1, stats + 0);
  norm_cl_kernel<<<dim3(512, B_), 256, 0, stream>>>(a1, stats + 0, agg_g1, agg_b1,
                                                    1.0 / (2.0 * DHW_));

  // agg conv2 (16->16) MFMA 3D-tile ; GN ; SiLU
  conv3d_mfma_kernel<16, 14><<<3200, 256, 0, stream>>>(a1, wf2, a2);
  stats_cl_kernel<<<dim3(256, B_), 256, 0, stream>>>(a2, stats + 32);
  norm_cl_kernel<<<dim3(512, B_), 256, 0, stream>>>(a2, stats + 32, agg_g2, agg_b2,
                                                    1.0 / (2.0 * DHW_));

  // agg conv3 (16->1) + bias -> logits (fp32, [B,D,H,W]), LDS-tiled
  conv3_tile_kernel<<<3200, 256, 0, stream>>>(a2, agg_w3, agg_bias3, logits);

  // softmax -> dsa (ws), conf (out)
  softmax_kernel<<<B_ * H_, 320, 0, stream>>>(logits, dsa, out_conf);

  // feat head: conv2d(64->16, 2 co-tiles) ; GN ; SiLU -> out_feat
  conv2d_kernel<C_, 0, 16, 2, false, false><<<dim3(B_ * H_, 2), 320, 0, stream>>>(
      fL, nullptr, feat_w, nullptr, nullptr, featraw);
  stats_kernel<<<B_ * 8 * 2 * 8, 256, 0, stream>>>(featraw, stats + 64, 16, 2, (size_t)HW_, 8);
  norm_silu_f32o_kernel<<<dim3(50, 16, B_), 256, 0, stream>>>(featraw, out_feat, stats + 64,
                                                              feat_g, feat_b, 2, (size_t)HW_,
                                                              1.0 / (2.0 * HW_));

  // apc conv1d on flattened logits
  conv1d_kernel<<<(B_ * HW_) / 256, 256, 0, stream>>>(logits, apc_w, apc);

  // regression head conv1 (24+16 -> 32, 4 co-tiles) ; GN ; SiLU
  conv2d_kernel<D_, 16, 32, 4, false, false><<<dim3(B_ * H_, 4), 320, 0, stream>>>(
      apc, out_feat, reg_w1, nullptr, nullptr, h2);
  stats_kernel<<<B_ * 8 * 4 * 8, 256, 0, stream>>>(h2, stats + 96, 32, 4, (size_t)HW_, 8);
  norm_silu_f32o_kernel<<<dim3(50, 32, B_), 256, 0, stream>>>(h2, h2, stats + 96, reg_g1, reg_b1,
                                                              4, (size_t)HW_, 1.0 / (4.0 * HW_));

  // regression conv2 (32->1) + bias + d_sa -> d_init
  conv2d_kernel<32, 0, 1, 1, true, true><<<dim3(B_ * H_, 1), 320, 0, stream>>>(
      h2, nullptr, reg_w2, reg_bias2, dsa, out_dinit);
}